// Round 3
// baseline (1739.557 us; speedup 1.0000x reference)
//
#include <hip/hip_runtime.h>
#include <hip/hip_bf16.h>

// EGATConv fused forward, f32, MI355X.
// Pipeline: memset(den,agg) -> k_proj(nproj,Psrc,Pdst) -> k_edge(f, a, ex, e_out,
// atomic den/agg scatter) -> k_node_out(h_out).
// Key algebra: stack@We split into Psrc[src] + ef@We_mid + Pdst[dst];
// a = f . rowsum(Wa); softmax max-shift skipped (|a| ~ 0.3, exp safe),
// normalization folded to node level: h = (sum ex*nproj[src]) / (sum ex).
// R1: A-operand LDS reads vectorized to ds_read_b128.
// R2 FIX: k_node_out sh staging loop ran q<4 (1024 float4) but sh is 64x128
// = 2048 float4 -> rows 32..63 uninitialized -> absmax 1.56. Now q<8.

#define NN 50000
#define NE 800000

__device__ __forceinline__ float lrelu(float x) { return x > 0.f ? x : 0.01f * x; }

// ---------------------------------------------------------------------------
// k_proj: out[mode] = nfeats @ W + (bias if mode 0)
//   mode 0: Wn rows 0..63     -> nproj  (+bn)
//   mode 1: We rows 0..63     -> Psrc
//   mode 2: We rows 128..191  -> Pdst
// block: 64 nodes x 128 outputs, 256 threads, thread tile 4n x (4+4)j
// ---------------------------------------------------------------------------
__global__ __launch_bounds__(256) void k_proj(
    const float* __restrict__ nf, const float* __restrict__ Wn,
    const float* __restrict__ bn, const float* __restrict__ We,
    float* __restrict__ nproj, float* __restrict__ Psrc, float* __restrict__ Pdst)
{
    __shared__ __align__(16) float sA[64 * 68];
    __shared__ __align__(16) float sW[64 * 128];
    const int tid = threadIdx.x;
    const int mode = blockIdx.y;
    const int nBase = blockIdx.x * 64;

    const float* W = (mode == 0) ? Wn : (mode == 1 ? We : We + 128 * 128);
    float* outp = (mode == 0) ? nproj : (mode == 1 ? Psrc : Pdst);

    // stage A rows [64][64] -> sA[64][68] (coalesced float4)
    #pragma unroll
    for (int q = 0; q < 4; ++q) {
        int idx = q * 256 + tid;
        int e = idx >> 4, c4 = idx & 15;
        int row = nBase + e;
        float4 v = make_float4(0.f, 0.f, 0.f, 0.f);
        if (row < NN) v = *reinterpret_cast<const float4*>(&nf[row * 64 + c4 * 4]);
        *reinterpret_cast<float4*>(&sA[e * 68 + c4 * 4]) = v;
    }
    // stage W [64][128] (linear copy)
    #pragma unroll
    for (int q = 0; q < 8; ++q) {
        int idx = q * 256 + tid;
        *reinterpret_cast<float4*>(&sW[idx * 4]) =
            *reinterpret_cast<const float4*>(&W[idx * 4]);
    }
    __syncthreads();

    const int jt = tid & 15, et = tid >> 4;
    float acc[4][8];
    #pragma unroll
    for (int i = 0; i < 4; ++i)
        #pragma unroll
        for (int j = 0; j < 8; ++j) acc[i][j] = 0.f;

    #pragma unroll 2
    for (int kk4 = 0; kk4 < 16; ++kk4) {
        float4 a4[4];
        #pragma unroll
        for (int i = 0; i < 4; ++i)
            a4[i] = *reinterpret_cast<const float4*>(&sA[(4 * et + i) * 68 + 4 * kk4]);
        #pragma unroll
        for (int c = 0; c < 4; ++c) {
            int kk = 4 * kk4 + c;
            float4 b0 = *reinterpret_cast<const float4*>(&sW[kk * 128 + 4 * jt]);
            float4 b1 = *reinterpret_cast<const float4*>(&sW[kk * 128 + 64 + 4 * jt]);
            #pragma unroll
            for (int i = 0; i < 4; ++i) {
                float av = (&a4[i].x)[c];
                acc[i][0] = fmaf(av, b0.x, acc[i][0]);
                acc[i][1] = fmaf(av, b0.y, acc[i][1]);
                acc[i][2] = fmaf(av, b0.z, acc[i][2]);
                acc[i][3] = fmaf(av, b0.w, acc[i][3]);
                acc[i][4] = fmaf(av, b1.x, acc[i][4]);
                acc[i][5] = fmaf(av, b1.y, acc[i][5]);
                acc[i][6] = fmaf(av, b1.z, acc[i][6]);
                acc[i][7] = fmaf(av, b1.w, acc[i][7]);
            }
        }
    }

    float4 bias0 = make_float4(0.f, 0.f, 0.f, 0.f), bias1 = bias0;
    if (mode == 0) {
        bias0 = *reinterpret_cast<const float4*>(&bn[4 * jt]);
        bias1 = *reinterpret_cast<const float4*>(&bn[64 + 4 * jt]);
    }
    #pragma unroll
    for (int i = 0; i < 4; ++i) {
        int row = nBase + 4 * et + i;
        if (row >= NN) continue;
        float4 r0 = make_float4(acc[i][0] + bias0.x, acc[i][1] + bias0.y,
                                acc[i][2] + bias0.z, acc[i][3] + bias0.w);
        float4 r1 = make_float4(acc[i][4] + bias1.x, acc[i][5] + bias1.y,
                                acc[i][6] + bias1.z, acc[i][7] + bias1.w);
        *reinterpret_cast<float4*>(&outp[row * 128 + 4 * jt]) = r0;
        *reinterpret_cast<float4*>(&outp[row * 128 + 64 + 4 * jt]) = r1;
    }
}

// ---------------------------------------------------------------------------
// k_edge: per 64-edge block:
//   f = lrelu(ef@We_mid + Psrc[src] + Pdst[dst])   (64x128)
//   a[e][h] = f[e][32h..] . wa_sum ; ex = exp(a) ; atomicAdd den[dst][h]
//   e_out = f @ Woe + boe
//   atomicAdd agg[dst][j] += ex[h(j)] * nproj[src][j]
// ---------------------------------------------------------------------------
__global__ __launch_bounds__(256) void k_edge(
    const float* __restrict__ ef, const int* __restrict__ src,
    const int* __restrict__ dst, const float* __restrict__ We,
    const float* __restrict__ Wa, const float* __restrict__ Woe,
    const float* __restrict__ boe, const float* __restrict__ nproj,
    const float* __restrict__ Psrc, const float* __restrict__ Pdst,
    float* __restrict__ den, float* __restrict__ agg, float* __restrict__ e_out)
{
    // union region: phase A: sA[64*68]=4352 | sW[64*128]=8192  (total 12544)
    //               phase B: sf[64*132]=8448 | sWoe[128*32]=4096 (total 12544)
    __shared__ __align__(16) float smem[12544];
    __shared__ __align__(16) int sidx[128];     // src[0..63], dst[64..127]
    __shared__ __align__(16) float swa[32];
    __shared__ __align__(16) float sboe[32];
    __shared__ __align__(16) float sex[256];    // ex [64][4]

    float* sA = smem;            // [64][68]
    float* sW = smem + 4352;     // [64][128]
    float* sf = smem;            // [64][132]
    float* sWoe = smem + 8448;   // [128][32]

    const int tid = threadIdx.x;
    const int eBase = blockIdx.x * 64;

    // ---- stage ef tile + We_mid + indices + wa_sum + boe ----
    #pragma unroll
    for (int q = 0; q < 4; ++q) {
        int idx = q * 256 + tid;
        int e = idx >> 4, c4 = idx & 15;
        *reinterpret_cast<float4*>(&sA[e * 68 + c4 * 4]) =
            *reinterpret_cast<const float4*>(&ef[(size_t)(eBase + e) * 64 + c4 * 4]);
    }
    #pragma unroll
    for (int q = 0; q < 8; ++q) {
        int idx = q * 256 + tid;
        *reinterpret_cast<float4*>(&sW[idx * 4]) =
            *reinterpret_cast<const float4*>(&We[64 * 128 + idx * 4]);
    }
    if (tid < 64) { sidx[tid] = src[eBase + tid]; sidx[64 + tid] = dst[eBase + tid]; }
    if (tid < 32) {
        float4 w = *reinterpret_cast<const float4*>(&Wa[tid * 4]);
        swa[tid] = w.x + w.y + w.z + w.w;
        sboe[tid] = boe[tid];
    }
    __syncthreads();

    // ---- main GEMM: acc[4e][8j], j in {4jt..4jt+3} u {64+4jt..+3} ----
    const int jt = tid & 15, et = tid >> 4;
    float acc[4][8];
    #pragma unroll
    for (int i = 0; i < 4; ++i)
        #pragma unroll
        for (int j = 0; j < 8; ++j) acc[i][j] = 0.f;

    #pragma unroll 2
    for (int kk4 = 0; kk4 < 16; ++kk4) {
        float4 a4[4];
        #pragma unroll
        for (int i = 0; i < 4; ++i)
            a4[i] = *reinterpret_cast<const float4*>(&sA[(4 * et + i) * 68 + 4 * kk4]);
        #pragma unroll
        for (int c = 0; c < 4; ++c) {
            int kk = 4 * kk4 + c;
            float4 b0 = *reinterpret_cast<const float4*>(&sW[kk * 128 + 4 * jt]);
            float4 b1 = *reinterpret_cast<const float4*>(&sW[kk * 128 + 64 + 4 * jt]);
            #pragma unroll
            for (int i = 0; i < 4; ++i) {
                float av = (&a4[i].x)[c];
                acc[i][0] = fmaf(av, b0.x, acc[i][0]);
                acc[i][1] = fmaf(av, b0.y, acc[i][1]);
                acc[i][2] = fmaf(av, b0.z, acc[i][2]);
                acc[i][3] = fmaf(av, b0.w, acc[i][3]);
                acc[i][4] = fmaf(av, b1.x, acc[i][4]);
                acc[i][5] = fmaf(av, b1.y, acc[i][5]);
                acc[i][6] = fmaf(av, b1.z, acc[i][6]);
                acc[i][7] = fmaf(av, b1.w, acc[i][7]);
            }
        }
    }
    __syncthreads();   // sA, sW dead

    // ---- epilogue: f = lrelu(acc + Psrc[s] + Pdst[d]) -> sf ----
    #pragma unroll
    for (int i = 0; i < 4; ++i) {
        int e = 4 * et + i;
        int s = sidx[e], d = sidx[64 + e];
        float4 ps0 = *reinterpret_cast<const float4*>(&Psrc[(size_t)s * 128 + 4 * jt]);
        float4 ps1 = *reinterpret_cast<const float4*>(&Psrc[(size_t)s * 128 + 64 + 4 * jt]);
        float4 pd0 = *reinterpret_cast<const float4*>(&Pdst[(size_t)d * 128 + 4 * jt]);
        float4 pd1 = *reinterpret_cast<const float4*>(&Pdst[(size_t)d * 128 + 64 + 4 * jt]);
        float4 f0, f1;
        f0.x = lrelu(acc[i][0] + ps0.x + pd0.x);
        f0.y = lrelu(acc[i][1] + ps0.y + pd0.y);
        f0.z = lrelu(acc[i][2] + ps0.z + pd0.z);
        f0.w = lrelu(acc[i][3] + ps0.w + pd0.w);
        f1.x = lrelu(acc[i][4] + ps1.x + pd1.x);
        f1.y = lrelu(acc[i][5] + ps1.y + pd1.y);
        f1.z = lrelu(acc[i][6] + ps1.z + pd1.z);
        f1.w = lrelu(acc[i][7] + ps1.w + pd1.w);
        *reinterpret_cast<float4*>(&sf[e * 132 + 4 * jt]) = f0;
        *reinterpret_cast<float4*>(&sf[e * 132 + 64 + 4 * jt]) = f1;
    }
    // stage Woe into sWoe (overlaps dead sW tail; we are past the barrier)
    #pragma unroll
    for (int q = 0; q < 4; ++q) {
        int idx = q * 256 + tid;
        *reinterpret_cast<float4*>(&sWoe[idx * 4]) =
            *reinterpret_cast<const float4*>(&Woe[idx * 4]);
    }
    __syncthreads();

    // ---- a / ex phase: thread = (e, h) ----
    {
        int e = tid >> 2, h = tid & 3;
        float a = 0.f;
        #pragma unroll
        for (int kk = 0; kk < 8; ++kk) {
            float4 fv = *reinterpret_cast<const float4*>(&sf[e * 132 + h * 32 + kk * 4]);
            float4 wv = *reinterpret_cast<const float4*>(&swa[kk * 4]);
            a = fmaf(fv.x, wv.x, a); a = fmaf(fv.y, wv.y, a);
            a = fmaf(fv.z, wv.z, a); a = fmaf(fv.w, wv.w, a);
        }
        float ex = expf(a);
        sex[e * 4 + h] = ex;
        atomicAdd(&den[(size_t)sidx[64 + e] * 4 + h], ex);
    }
    __syncthreads();

    // ---- e_out phase: thread = (e, q), 8 outputs ----
    {
        int e = tid >> 2, q = tid & 3;
        int j0 = q * 8;
        float4 r0 = make_float4(0.f, 0.f, 0.f, 0.f), r1 = r0;
        #pragma unroll 4
        for (int k = 0; k < 128; k += 4) {
            float4 fv = *reinterpret_cast<const float4*>(&sf[e * 132 + k]);
            #pragma unroll
            for (int c = 0; c < 4; ++c) {
                float fk = (&fv.x)[c];
                float4 w0 = *reinterpret_cast<const float4*>(&sWoe[(k + c) * 32 + j0]);
                float4 w1 = *reinterpret_cast<const float4*>(&sWoe[(k + c) * 32 + j0 + 4]);
                r0.x = fmaf(fk, w0.x, r0.x); r0.y = fmaf(fk, w0.y, r0.y);
                r0.z = fmaf(fk, w0.z, r0.z); r0.w = fmaf(fk, w0.w, r0.w);
                r1.x = fmaf(fk, w1.x, r1.x); r1.y = fmaf(fk, w1.y, r1.y);
                r1.z = fmaf(fk, w1.z, r1.z); r1.w = fmaf(fk, w1.w, r1.w);
            }
        }
        float4 b0 = *reinterpret_cast<const float4*>(&sboe[j0]);
        float4 b1 = *reinterpret_cast<const float4*>(&sboe[j0 + 4]);
        r0.x += b0.x; r0.y += b0.y; r0.z += b0.z; r0.w += b0.w;
        r1.x += b1.x; r1.y += b1.y; r1.z += b1.z; r1.w += b1.w;
        size_t o = (size_t)(eBase + e) * 32 + j0;
        *reinterpret_cast<float4*>(&e_out[o]) = r0;
        *reinterpret_cast<float4*>(&e_out[o + 4]) = r1;
    }

    // ---- message scatter: agg[d][j] += ex[e][h(j)] * nproj[s][j] ----
    {
        int h0 = jt >> 3;          // quad0: j = 4jt in [0,64): h = j>>5 = jt>>3
        #pragma unroll
        for (int i = 0; i < 4; ++i) {
            int e = 4 * et + i;
            int s = sidx[e], d = sidx[64 + e];
            float ex0 = sex[e * 4 + h0];
            float ex1 = sex[e * 4 + 2 + h0];
            float4 np0 = *reinterpret_cast<const float4*>(&nproj[(size_t)s * 128 + 4 * jt]);
            float4 np1 = *reinterpret_cast<const float4*>(&nproj[(size_t)s * 128 + 64 + 4 * jt]);
            float* ap0 = &agg[(size_t)d * 128 + 4 * jt];
            float* ap1 = &agg[(size_t)d * 128 + 64 + 4 * jt];
            atomicAdd(ap0 + 0, ex0 * np0.x);
            atomicAdd(ap0 + 1, ex0 * np0.y);
            atomicAdd(ap0 + 2, ex0 * np0.z);
            atomicAdd(ap0 + 3, ex0 * np0.w);
            atomicAdd(ap1 + 0, ex1 * np1.x);
            atomicAdd(ap1 + 1, ex1 * np1.y);
            atomicAdd(ap1 + 2, ex1 * np1.z);
            atomicAdd(ap1 + 3, ex1 * np1.w);
        }
    }
}

// ---------------------------------------------------------------------------
// k_node_out: h = den>0 ? agg/den : nproj ; h_out = h @ Won + bon
// ---------------------------------------------------------------------------
__global__ __launch_bounds__(256) void k_node_out(
    const float* __restrict__ agg, const float* __restrict__ den,
    const float* __restrict__ nproj, const float* __restrict__ Won,
    const float* __restrict__ bon, float* __restrict__ h_out)
{
    __shared__ __align__(16) float sh[64 * 132];
    __shared__ __align__(16) float sWon[128 * 32];
    __shared__ __align__(16) float sbon[32];
    const int tid = threadIdx.x;
    const int nBase = blockIdx.x * 64;

    // stage h rows: 64 rows x 32 float4 = 2048 float4 -> q<8 (R2 fix)
    #pragma unroll
    for (int q = 0; q < 8; ++q) {
        int idx = q * 256 + tid;
        int n = idx >> 5, c4 = idx & 31;
        int row = nBase + n;
        float4 v = make_float4(0.f, 0.f, 0.f, 0.f);
        if (row < NN) {
            float dd = den[(size_t)row * 4 + (c4 >> 3)];
            float4 a = *reinterpret_cast<const float4*>(&agg[(size_t)row * 128 + c4 * 4]);
            float4 p = *reinterpret_cast<const float4*>(&nproj[(size_t)row * 128 + c4 * 4]);
            if (dd > 0.f) v = make_float4(a.x / dd, a.y / dd, a.z / dd, a.w / dd);
            else v = p;
        }
        *reinterpret_cast<float4*>(&sh[n * 132 + c4 * 4]) = v;
    }
    #pragma unroll
    for (int q = 0; q < 4; ++q) {
        int idx = q * 256 + tid;
        *reinterpret_cast<float4*>(&sWon[idx * 4]) =
            *reinterpret_cast<const float4*>(&Won[idx * 4]);
    }
    if (tid < 32) sbon[tid] = bon[tid];
    __syncthreads();

    int n = tid >> 2, q = tid & 3;
    int j0 = q * 8;
    int row = nBase + n;
    float4 r0 = make_float4(0.f, 0.f, 0.f, 0.f), r1 = r0;
    #pragma unroll 4
    for (int k = 0; k < 128; k += 4) {
        float4 fv = *reinterpret_cast<const float4*>(&sh[n * 132 + k]);
        #pragma unroll
        for (int c = 0; c < 4; ++c) {
            float fk = (&fv.x)[c];
            float4 w0 = *reinterpret_cast<const float4*>(&sWon[(k + c) * 32 + j0]);
            float4 w1 = *reinterpret_cast<const float4*>(&sWon[(k + c) * 32 + j0 + 4]);
            r0.x = fmaf(fk, w0.x, r0.x); r0.y = fmaf(fk, w0.y, r0.y);
            r0.z = fmaf(fk, w0.z, r0.z); r0.w = fmaf(fk, w0.w, r0.w);
            r1.x = fmaf(fk, w1.x, r1.x); r1.y = fmaf(fk, w1.y, r1.y);
            r1.z = fmaf(fk, w1.z, r1.z); r1.w = fmaf(fk, w1.w, r1.w);
        }
    }
    if (row < NN) {
        float4 b0 = *reinterpret_cast<const float4*>(&sbon[j0]);
        float4 b1 = *reinterpret_cast<const float4*>(&sbon[j0 + 4]);
        r0.x += b0.x; r0.y += b0.y; r0.z += b0.z; r0.w += b0.w;
        r1.x += b1.x; r1.y += b1.y; r1.z += b1.z; r1.w += b1.w;
        size_t o = (size_t)row * 32 + j0;
        *reinterpret_cast<float4*>(&h_out[o]) = r0;
        *reinterpret_cast<float4*>(&h_out[o + 4]) = r1;
    }
}

extern "C" void kernel_launch(void* const* d_in, const int* in_sizes, int n_in,
                              void* d_out, int out_size, void* d_ws, size_t ws_size,
                              hipStream_t stream) {
    const float* nfeats = (const float*)d_in[0];
    const float* efeats = (const float*)d_in[1];
    const int*   src    = (const int*)d_in[2];
    const int*   dst    = (const int*)d_in[3];
    const float* Wn     = (const float*)d_in[4];
    const float* bn     = (const float*)d_in[5];
    const float* We     = (const float*)d_in[6];
    const float* Wa     = (const float*)d_in[7];
    const float* Won    = (const float*)d_in[8];
    const float* bon    = (const float*)d_in[9];
    const float* Woe    = (const float*)d_in[10];
    const float* boe    = (const float*)d_in[11];

    float* h_out = (float*)d_out;                 // [N,32]
    float* e_out = h_out + (size_t)NN * 32;       // [E,32]

    // ws layout (floats): agg[N*128] | den[N*4] | nproj[N*128] | Psrc[N*128] | Pdst[N*128]
    float* agg   = (float*)d_ws;
    float* den   = agg + (size_t)NN * 128;
    float* nproj = den + (size_t)NN * 4;
    float* Psrc  = nproj + (size_t)NN * 128;
    float* Pdst  = Psrc + (size_t)NN * 128;

    // zero agg+den (contiguous prefix)
    hipMemsetAsync(d_ws, 0, (size_t)NN * (128 + 4) * sizeof(float), stream);

    dim3 gProj((NN + 63) / 64, 3);
    k_proj<<<gProj, 256, 0, stream>>>(nfeats, Wn, bn, We, nproj, Psrc, Pdst);

    k_edge<<<NE / 64, 256, 0, stream>>>(efeats, src, dst, We, Wa, Woe, boe,
                                        nproj, Psrc, Pdst, den, agg, e_out);

    k_node_out<<<(NN + 63) / 64, 256, 0, stream>>>(agg, den, nproj, Won, bon, h_out);
}

// Round 4
// 812.776 us; speedup vs baseline: 2.1403x; 2.1403x over previous
//
#include <hip/hip_runtime.h>
#include <hip/hip_bf16.h>

// EGATConv fused forward, f32, MI355X.
// R3 restructure: dst-CSR replaces the 102.4M-atomicAdd agg scatter.
//   memset(deg) -> k_count -> k_scan(rowptr,cursor) -> k_proj(nproj,Psrc,Pdst)
//   -> k_edge(f GEMM, a/ex, CSR-fill srcs/exs, e_out)  [no f32 atomics]
//   -> k_agg(per-node gather: h = sum(ex*nproj[src])/sum(ex), deg0 fallback)
//   -> k_node_out(hbuf @ Won + bon).
// Evidence: R3 profile showed k_edge WRITE_SIZE=1.725GB, VALUBusy=12% ->
// atomic-bound (~1.25ms stall). CSR converts scatter to coalesced gathers.
// Algebra (unchanged): stack@We = Psrc[src] + ef@We_mid + Pdst[dst];
// a = f . rowsum(Wa); softmax max-shift skipped (|a|~0.3), normalization at
// node level.

#define NN 50000
#define NE 800000

__device__ __forceinline__ float lrelu(float x) { return x > 0.f ? x : 0.01f * x; }

// ---------------------------------------------------------------------------
// k_count: deg[n] = #edges with dst==n
// ---------------------------------------------------------------------------
__global__ __launch_bounds__(256) void k_count(const int* __restrict__ dst,
                                               int* __restrict__ deg)
{
    int i = blockIdx.x * blockDim.x + threadIdx.x;
    int stride = gridDim.x * blockDim.x;
    for (; i < NE; i += stride) atomicAdd(&deg[dst[i]], 1);
}

// ---------------------------------------------------------------------------
// k_scan: exclusive prefix sum of deg -> rowptr[0..N], cursor (copy).
// Single block, 1024 threads, wave-shfl scan (2 barriers/chunk).
// ---------------------------------------------------------------------------
__global__ __launch_bounds__(1024) void k_scan(const int* __restrict__ deg,
                                               int* __restrict__ rowptr,
                                               int* __restrict__ cursor)
{
    __shared__ int wsum[16];
    __shared__ int sbase;
    const int tid = threadIdx.x;
    const int lane = tid & 63, wid = tid >> 6;
    if (tid == 0) sbase = 0;
    __syncthreads();
    const int nchunk = (NN + 1023) / 1024;
    for (int c = 0; c < nchunk; ++c) {
        int i = c * 1024 + tid;
        int v = (i < NN) ? deg[i] : 0;
        int x = v;
        #pragma unroll
        for (int off = 1; off < 64; off <<= 1) {
            int t = __shfl_up(x, off);
            if (lane >= off) x += t;
        }
        if (lane == 63) wsum[wid] = x;
        __syncthreads();
        if (wid == 0) {
            int w = (lane < 16) ? wsum[lane] : 0;
            #pragma unroll
            for (int off = 1; off < 16; off <<= 1) {
                int t = __shfl_up(w, off);
                if (lane >= off) w += t;
            }
            if (lane < 16) wsum[lane] = w;   // inclusive wave sums
        }
        __syncthreads();
        int waveoff = (wid == 0) ? 0 : wsum[wid - 1];
        int excl = sbase + waveoff + x - v;
        if (i < NN) { rowptr[i] = excl; cursor[i] = excl; }
        __syncthreads();                     // protect sbase/wsum reads
        if (tid == 0) sbase += wsum[15];
        __syncthreads();
    }
    if (tid == 0) rowptr[NN] = sbase;        // == NE
}

// ---------------------------------------------------------------------------
// k_proj: out[mode] = nfeats @ W + (bias if mode 0)
//   mode 0: Wn -> nproj (+bn) ; mode 1: We[0:64] -> Psrc ; mode 2: We[128:192] -> Pdst
// ---------------------------------------------------------------------------
__global__ __launch_bounds__(256) void k_proj(
    const float* __restrict__ nf, const float* __restrict__ Wn,
    const float* __restrict__ bn, const float* __restrict__ We,
    float* __restrict__ nproj, float* __restrict__ Psrc, float* __restrict__ Pdst)
{
    __shared__ __align__(16) float sA[64 * 68];
    __shared__ __align__(16) float sW[64 * 128];
    const int tid = threadIdx.x;
    const int mode = blockIdx.y;
    const int nBase = blockIdx.x * 64;

    const float* W = (mode == 0) ? Wn : (mode == 1 ? We : We + 128 * 128);
    float* outp = (mode == 0) ? nproj : (mode == 1 ? Psrc : Pdst);

    #pragma unroll
    for (int q = 0; q < 4; ++q) {
        int idx = q * 256 + tid;
        int e = idx >> 4, c4 = idx & 15;
        int row = nBase + e;
        float4 v = make_float4(0.f, 0.f, 0.f, 0.f);
        if (row < NN) v = *reinterpret_cast<const float4*>(&nf[row * 64 + c4 * 4]);
        *reinterpret_cast<float4*>(&sA[e * 68 + c4 * 4]) = v;
    }
    #pragma unroll
    for (int q = 0; q < 8; ++q) {
        int idx = q * 256 + tid;
        *reinterpret_cast<float4*>(&sW[idx * 4]) =
            *reinterpret_cast<const float4*>(&W[idx * 4]);
    }
    __syncthreads();

    const int jt = tid & 15, et = tid >> 4;
    float acc[4][8];
    #pragma unroll
    for (int i = 0; i < 4; ++i)
        #pragma unroll
        for (int j = 0; j < 8; ++j) acc[i][j] = 0.f;

    #pragma unroll 2
    for (int kk4 = 0; kk4 < 16; ++kk4) {
        float4 a4[4];
        #pragma unroll
        for (int i = 0; i < 4; ++i)
            a4[i] = *reinterpret_cast<const float4*>(&sA[(4 * et + i) * 68 + 4 * kk4]);
        #pragma unroll
        for (int c = 0; c < 4; ++c) {
            int kk = 4 * kk4 + c;
            float4 b0 = *reinterpret_cast<const float4*>(&sW[kk * 128 + 4 * jt]);
            float4 b1 = *reinterpret_cast<const float4*>(&sW[kk * 128 + 64 + 4 * jt]);
            #pragma unroll
            for (int i = 0; i < 4; ++i) {
                float av = (&a4[i].x)[c];
                acc[i][0] = fmaf(av, b0.x, acc[i][0]);
                acc[i][1] = fmaf(av, b0.y, acc[i][1]);
                acc[i][2] = fmaf(av, b0.z, acc[i][2]);
                acc[i][3] = fmaf(av, b0.w, acc[i][3]);
                acc[i][4] = fmaf(av, b1.x, acc[i][4]);
                acc[i][5] = fmaf(av, b1.y, acc[i][5]);
                acc[i][6] = fmaf(av, b1.z, acc[i][6]);
                acc[i][7] = fmaf(av, b1.w, acc[i][7]);
            }
        }
    }

    float4 bias0 = make_float4(0.f, 0.f, 0.f, 0.f), bias1 = bias0;
    if (mode == 0) {
        bias0 = *reinterpret_cast<const float4*>(&bn[4 * jt]);
        bias1 = *reinterpret_cast<const float4*>(&bn[64 + 4 * jt]);
    }
    #pragma unroll
    for (int i = 0; i < 4; ++i) {
        int row = nBase + 4 * et + i;
        if (row >= NN) continue;
        float4 r0 = make_float4(acc[i][0] + bias0.x, acc[i][1] + bias0.y,
                                acc[i][2] + bias0.z, acc[i][3] + bias0.w);
        float4 r1 = make_float4(acc[i][4] + bias1.x, acc[i][5] + bias1.y,
                                acc[i][6] + bias1.z, acc[i][7] + bias1.w);
        *reinterpret_cast<float4*>(&outp[row * 128 + 4 * jt]) = r0;
        *reinterpret_cast<float4*>(&outp[row * 128 + 64 + 4 * jt]) = r1;
    }
}

// ---------------------------------------------------------------------------
// k_edge: per 64-edge block:
//   f = lrelu(ef@We_mid + Psrc[src] + Pdst[dst])   (64x128)
//   a[e][h] = f[e][32h..] . wa_sum ; ex = exp(a)
//   CSR fill: pos = cursor[dst]++ ; srcs[pos]=src ; exs[pos][h]=ex
//   e_out = f @ Woe + boe
// ---------------------------------------------------------------------------
__global__ __launch_bounds__(256) void k_edge(
    const float* __restrict__ ef, const int* __restrict__ src,
    const int* __restrict__ dst, const float* __restrict__ We,
    const float* __restrict__ Wa, const float* __restrict__ Woe,
    const float* __restrict__ boe,
    const float* __restrict__ Psrc, const float* __restrict__ Pdst,
    int* __restrict__ cursor, int* __restrict__ srcs,
    float* __restrict__ exs, float* __restrict__ e_out)
{
    // union: phase A: sA[64*68] | sW[64*128]  (12544 floats)
    //        phase B: sf[64*132] | sWoe[128*32] (12544 floats)
    __shared__ __align__(16) float smem[12544];
    __shared__ __align__(16) int sidx[128];     // src[0..63], dst[64..127]
    __shared__ __align__(16) float swa[32];
    __shared__ __align__(16) float sboe[32];
    __shared__ __align__(16) int spos[64];      // CSR slot per edge

    float* sA = smem;            // [64][68]
    float* sW = smem + 4352;     // [64][128]
    float* sf = smem;            // [64][132]
    float* sWoe = smem + 8448;   // [128][32]

    const int tid = threadIdx.x;
    const int eBase = blockIdx.x * 64;

    // ---- stage ef tile + We_mid + indices + wa_sum + boe ----
    #pragma unroll
    for (int q = 0; q < 4; ++q) {
        int idx = q * 256 + tid;
        int e = idx >> 4, c4 = idx & 15;
        *reinterpret_cast<float4*>(&sA[e * 68 + c4 * 4]) =
            *reinterpret_cast<const float4*>(&ef[(size_t)(eBase + e) * 64 + c4 * 4]);
    }
    #pragma unroll
    for (int q = 0; q < 8; ++q) {
        int idx = q * 256 + tid;
        *reinterpret_cast<float4*>(&sW[idx * 4]) =
            *reinterpret_cast<const float4*>(&We[64 * 128 + idx * 4]);
    }
    if (tid < 64) { sidx[tid] = src[eBase + tid]; sidx[64 + tid] = dst[eBase + tid]; }
    if (tid < 32) {
        float4 w = *reinterpret_cast<const float4*>(&Wa[tid * 4]);
        swa[tid] = w.x + w.y + w.z + w.w;
        sboe[tid] = boe[tid];
    }
    __syncthreads();

    // ---- main GEMM: acc[4e][8j] ----
    const int jt = tid & 15, et = tid >> 4;
    float acc[4][8];
    #pragma unroll
    for (int i = 0; i < 4; ++i)
        #pragma unroll
        for (int j = 0; j < 8; ++j) acc[i][j] = 0.f;

    #pragma unroll 2
    for (int kk4 = 0; kk4 < 16; ++kk4) {
        float4 a4[4];
        #pragma unroll
        for (int i = 0; i < 4; ++i)
            a4[i] = *reinterpret_cast<const float4*>(&sA[(4 * et + i) * 68 + 4 * kk4]);
        #pragma unroll
        for (int c = 0; c < 4; ++c) {
            int kk = 4 * kk4 + c;
            float4 b0 = *reinterpret_cast<const float4*>(&sW[kk * 128 + 4 * jt]);
            float4 b1 = *reinterpret_cast<const float4*>(&sW[kk * 128 + 64 + 4 * jt]);
            #pragma unroll
            for (int i = 0; i < 4; ++i) {
                float av = (&a4[i].x)[c];
                acc[i][0] = fmaf(av, b0.x, acc[i][0]);
                acc[i][1] = fmaf(av, b0.y, acc[i][1]);
                acc[i][2] = fmaf(av, b0.z, acc[i][2]);
                acc[i][3] = fmaf(av, b0.w, acc[i][3]);
                acc[i][4] = fmaf(av, b1.x, acc[i][4]);
                acc[i][5] = fmaf(av, b1.y, acc[i][5]);
                acc[i][6] = fmaf(av, b1.z, acc[i][6]);
                acc[i][7] = fmaf(av, b1.w, acc[i][7]);
            }
        }
    }
    __syncthreads();   // sA, sW dead

    // ---- epilogue: f = lrelu(acc + Psrc[s] + Pdst[d]) -> sf ----
    #pragma unroll
    for (int i = 0; i < 4; ++i) {
        int e = 4 * et + i;
        int s = sidx[e], d = sidx[64 + e];
        float4 ps0 = *reinterpret_cast<const float4*>(&Psrc[(size_t)s * 128 + 4 * jt]);
        float4 ps1 = *reinterpret_cast<const float4*>(&Psrc[(size_t)s * 128 + 64 + 4 * jt]);
        float4 pd0 = *reinterpret_cast<const float4*>(&Pdst[(size_t)d * 128 + 4 * jt]);
        float4 pd1 = *reinterpret_cast<const float4*>(&Pdst[(size_t)d * 128 + 64 + 4 * jt]);
        float4 f0, f1;
        f0.x = lrelu(acc[i][0] + ps0.x + pd0.x);
        f0.y = lrelu(acc[i][1] + ps0.y + pd0.y);
        f0.z = lrelu(acc[i][2] + ps0.z + pd0.z);
        f0.w = lrelu(acc[i][3] + ps0.w + pd0.w);
        f1.x = lrelu(acc[i][4] + ps1.x + pd1.x);
        f1.y = lrelu(acc[i][5] + ps1.y + pd1.y);
        f1.z = lrelu(acc[i][6] + ps1.z + pd1.z);
        f1.w = lrelu(acc[i][7] + ps1.w + pd1.w);
        *reinterpret_cast<float4*>(&sf[e * 132 + 4 * jt]) = f0;
        *reinterpret_cast<float4*>(&sf[e * 132 + 64 + 4 * jt]) = f1;
    }
    // stage Woe (sW region is dead, past the barrier)
    #pragma unroll
    for (int q = 0; q < 4; ++q) {
        int idx = q * 256 + tid;
        *reinterpret_cast<float4*>(&sWoe[idx * 4]) =
            *reinterpret_cast<const float4*>(&Woe[idx * 4]);
    }
    __syncthreads();

    // ---- a / ex phase + CSR fill: thread = (e, h) ----
    {
        int e = tid >> 2, h = tid & 3;
        float a = 0.f;
        #pragma unroll
        for (int kk = 0; kk < 8; ++kk) {
            float4 fv = *reinterpret_cast<const float4*>(&sf[e * 132 + h * 32 + kk * 4]);
            float4 wv = *reinterpret_cast<const float4*>(&swa[kk * 4]);
            a = fmaf(fv.x, wv.x, a); a = fmaf(fv.y, wv.y, a);
            a = fmaf(fv.z, wv.z, a); a = fmaf(fv.w, wv.w, a);
        }
        float ex = expf(a);
        int d = sidx[64 + e];
        if (h == 0) spos[e] = atomicAdd(&cursor[d], 1);
        __syncthreads();
        int pos = spos[e];
        exs[(size_t)pos * 4 + h] = ex;
        if (h == 0) srcs[pos] = sidx[e];
    }

    // ---- e_out phase: thread = (e, q), 8 outputs ----
    {
        int e = tid >> 2, q = tid & 3;
        int j0 = q * 8;
        float4 r0 = make_float4(0.f, 0.f, 0.f, 0.f), r1 = r0;
        #pragma unroll 4
        for (int k = 0; k < 128; k += 4) {
            float4 fv = *reinterpret_cast<const float4*>(&sf[e * 132 + k]);
            #pragma unroll
            for (int c = 0; c < 4; ++c) {
                float fk = (&fv.x)[c];
                float4 w0 = *reinterpret_cast<const float4*>(&sWoe[(k + c) * 32 + j0]);
                float4 w1 = *reinterpret_cast<const float4*>(&sWoe[(k + c) * 32 + j0 + 4]);
                r0.x = fmaf(fk, w0.x, r0.x); r0.y = fmaf(fk, w0.y, r0.y);
                r0.z = fmaf(fk, w0.z, r0.z); r0.w = fmaf(fk, w0.w, r0.w);
                r1.x = fmaf(fk, w1.x, r1.x); r1.y = fmaf(fk, w1.y, r1.y);
                r1.z = fmaf(fk, w1.z, r1.z); r1.w = fmaf(fk, w1.w, r1.w);
            }
        }
        float4 b0 = *reinterpret_cast<const float4*>(&sboe[j0]);
        float4 b1 = *reinterpret_cast<const float4*>(&sboe[j0 + 4]);
        r0.x += b0.x; r0.y += b0.y; r0.z += b0.z; r0.w += b0.w;
        r1.x += b1.x; r1.y += b1.y; r1.z += b1.z; r1.w += b1.w;
        size_t o = (size_t)(eBase + e) * 32 + j0;
        *reinterpret_cast<float4*>(&e_out[o]) = r0;
        *reinterpret_cast<float4*>(&e_out[o + 4]) = r1;
    }
}

// ---------------------------------------------------------------------------
// k_agg: per node n (2 nodes/block, 128 threads each, thread owns output j):
//   val = sum_p exs[p][j>>5] * nproj[srcs[p]][j] ; den = sum_p exs[p][j>>5]
//   hbuf[n][j] = deg>0 ? val/den : nproj[n][j]
// ---------------------------------------------------------------------------
__global__ __launch_bounds__(256) void k_agg(
    const int* __restrict__ rowptr, const int* __restrict__ srcs,
    const float* __restrict__ exs, const float* __restrict__ nproj,
    float* __restrict__ hbuf)
{
    const int tid = threadIdx.x;
    const int j = tid & 127;
    const int n = blockIdx.x * 2 + (tid >> 7);
    if (n >= NN) return;
    const int beg = rowptr[n], end = rowptr[n + 1];
    const int h = j >> 5;
    float val = 0.f, den = 0.f;
    int s_next = (beg < end) ? srcs[beg] : 0;
    for (int p = beg; p < end; ++p) {
        int s = s_next;
        if (p + 1 < end) s_next = srcs[p + 1];
        float ex = exs[(size_t)p * 4 + h];
        val = fmaf(ex, nproj[(size_t)s * 128 + j], val);
        den += ex;
    }
    float out = (end > beg) ? (val / den) : nproj[(size_t)n * 128 + j];
    hbuf[(size_t)n * 128 + j] = out;
}

// ---------------------------------------------------------------------------
// k_node_out: h_out = hbuf @ Won + bon
// ---------------------------------------------------------------------------
__global__ __launch_bounds__(256) void k_node_out(
    const float* __restrict__ hbuf, const float* __restrict__ Won,
    const float* __restrict__ bon, float* __restrict__ h_out)
{
    __shared__ __align__(16) float sh[64 * 132];
    __shared__ __align__(16) float sWon[128 * 32];
    __shared__ __align__(16) float sbon[32];
    const int tid = threadIdx.x;
    const int nBase = blockIdx.x * 64;

    // 64 rows x 32 float4 = 2048 -> q<8
    #pragma unroll
    for (int q = 0; q < 8; ++q) {
        int idx = q * 256 + tid;
        int n = idx >> 5, c4 = idx & 31;
        int row = nBase + n;
        float4 v = make_float4(0.f, 0.f, 0.f, 0.f);
        if (row < NN)
            v = *reinterpret_cast<const float4*>(&hbuf[(size_t)row * 128 + c4 * 4]);
        *reinterpret_cast<float4*>(&sh[n * 132 + c4 * 4]) = v;
    }
    #pragma unroll
    for (int q = 0; q < 4; ++q) {
        int idx = q * 256 + tid;
        *reinterpret_cast<float4*>(&sWon[idx * 4]) =
            *reinterpret_cast<const float4*>(&Won[idx * 4]);
    }
    if (tid < 32) sbon[tid] = bon[tid];
    __syncthreads();

    int n = tid >> 2, q = tid & 3;
    int j0 = q * 8;
    int row = nBase + n;
    float4 r0 = make_float4(0.f, 0.f, 0.f, 0.f), r1 = r0;
    #pragma unroll 4
    for (int k = 0; k < 128; k += 4) {
        float4 fv = *reinterpret_cast<const float4*>(&sh[n * 132 + k]);
        #pragma unroll
        for (int c = 0; c < 4; ++c) {
            float fk = (&fv.x)[c];
            float4 w0 = *reinterpret_cast<const float4*>(&sWon[(k + c) * 32 + j0]);
            float4 w1 = *reinterpret_cast<const float4*>(&sWon[(k + c) * 32 + j0 + 4]);
            r0.x = fmaf(fk, w0.x, r0.x); r0.y = fmaf(fk, w0.y, r0.y);
            r0.z = fmaf(fk, w0.z, r0.z); r0.w = fmaf(fk, w0.w, r0.w);
            r1.x = fmaf(fk, w1.x, r1.x); r1.y = fmaf(fk, w1.y, r1.y);
            r1.z = fmaf(fk, w1.z, r1.z); r1.w = fmaf(fk, w1.w, r1.w);
        }
    }
    if (row < NN) {
        float4 b0 = *reinterpret_cast<const float4*>(&sbon[j0]);
        float4 b1 = *reinterpret_cast<const float4*>(&sbon[j0 + 4]);
        r0.x += b0.x; r0.y += b0.y; r0.z += b0.z; r0.w += b0.w;
        r1.x += b1.x; r1.y += b1.y; r1.z += b1.z; r1.w += b1.w;
        size_t o = (size_t)row * 32 + j0;
        *reinterpret_cast<float4*>(&h_out[o]) = r0;
        *reinterpret_cast<float4*>(&h_out[o + 4]) = r1;
    }
}

extern "C" void kernel_launch(void* const* d_in, const int* in_sizes, int n_in,
                              void* d_out, int out_size, void* d_ws, size_t ws_size,
                              hipStream_t stream) {
    const float* nfeats = (const float*)d_in[0];
    const float* efeats = (const float*)d_in[1];
    const int*   src    = (const int*)d_in[2];
    const int*   dst    = (const int*)d_in[3];
    const float* Wn     = (const float*)d_in[4];
    const float* bn     = (const float*)d_in[5];
    const float* We     = (const float*)d_in[6];
    const float* Wa     = (const float*)d_in[7];
    const float* Won    = (const float*)d_in[8];
    const float* bon    = (const float*)d_in[9];
    const float* Woe    = (const float*)d_in[10];
    const float* boe    = (const float*)d_in[11];

    float* h_out = (float*)d_out;                 // [N,32]
    float* e_out = h_out + (size_t)NN * 32;       // [E,32]

    // ws layout: nproj[N*128]f | Psrc[N*128]f (hbuf aliases after k_edge) |
    //            Pdst[N*128]f | exs[E*4]f | deg[N]i | rowptr[N+1]i |
    //            cursor[N]i | srcs[E]i            (~93 MB total)
    float* nproj  = (float*)d_ws;
    float* Psrc   = nproj + (size_t)NN * 128;
    float* Pdst   = Psrc + (size_t)NN * 128;
    float* exs    = Pdst + (size_t)NN * 128;
    int*   deg    = (int*)(exs + (size_t)NE * 4);
    int*   rowptr = deg + NN;
    int*   cursor = rowptr + NN + 1;
    int*   srcs   = cursor + NN;
    float* hbuf   = Psrc;                         // Psrc dead after k_edge

    hipMemsetAsync(deg, 0, NN * sizeof(int), stream);

    k_count<<<1024, 256, 0, stream>>>(dst, deg);
    k_scan<<<1, 1024, 0, stream>>>(deg, rowptr, cursor);

    dim3 gProj((NN + 63) / 64, 3);
    k_proj<<<gProj, 256, 0, stream>>>(nfeats, Wn, bn, We, nproj, Psrc, Pdst);

    k_edge<<<NE / 64, 256, 0, stream>>>(efeats, src, dst, We, Wa, Woe, boe,
                                        Psrc, Pdst, cursor, srcs, exs, e_out);

    k_agg<<<(NN + 1) / 2, 256, 0, stream>>>(rowptr, srcs, exs, nproj, hbuf);

    k_node_out<<<(NN + 63) / 64, 256, 0, stream>>>(hbuf, Won, bon, h_out);
}

// Round 5
// 810.457 us; speedup vs baseline: 2.1464x; 1.0029x over previous
//
#include <hip/hip_runtime.h>
#include <hip/hip_bf16.h>

// EGATConv fused forward, f32, MI355X.
// R3: dst-CSR replaced 102.4M f32 atomics (k_edge 1451->343us, WRITE 1.7G->175M).
// R4: (a) single-block k_scan (serial, ~1 CU) -> 3-kernel parallel scan;
//     (b) k_edge: Psrc/Pdst row gathers hoisted into registers BEFORE the
//         GEMM (T14 issue-early/consume-late) so L3 latency hides under FMA.
// Pipeline: memset(deg) -> k_count -> scan_blk/top/add -> k_proj
//   -> k_edge(f GEMM, a/ex, CSR-fill, e_out) -> k_agg -> k_node_out.
// Algebra: stack@We = Psrc[src] + ef@We_mid + Pdst[dst]; a = f . rowsum(Wa);
// softmax max-shift skipped (|a|~0.3); normalization folded to node level.

#define NN 50000
#define NE 800000
#define NB ((NN + 255) / 256)   // 196 scan blocks

__device__ __forceinline__ float lrelu(float x) { return x > 0.f ? x : 0.01f * x; }

// ---------------------------------------------------------------------------
// k_count: deg[n] = #edges with dst==n
// ---------------------------------------------------------------------------
__global__ __launch_bounds__(256) void k_count(const int* __restrict__ dst,
                                               int* __restrict__ deg)
{
    int i = blockIdx.x * blockDim.x + threadIdx.x;
    int stride = gridDim.x * blockDim.x;
    for (; i < NE; i += stride) atomicAdd(&deg[dst[i]], 1);
}

// ---------------------------------------------------------------------------
// 3-kernel exclusive scan of deg[NN] -> rowptr/cursor (R4: replaces the
// single-block 50-chunk serial scan).
// ---------------------------------------------------------------------------
__global__ __launch_bounds__(256) void k_scan_blk(const int* __restrict__ deg,
                                                  int* __restrict__ rowptr,
                                                  int* __restrict__ bsum)
{
    __shared__ int wsum[4];
    const int tid = threadIdx.x, lane = tid & 63, wid = tid >> 6;
    const int i = blockIdx.x * 256 + tid;
    int v = (i < NN) ? deg[i] : 0;
    int x = v;
    #pragma unroll
    for (int off = 1; off < 64; off <<= 1) {
        int t = __shfl_up(x, off);
        if (lane >= off) x += t;
    }
    if (lane == 63) wsum[wid] = x;
    __syncthreads();
    if (tid == 0) {
        int s = 0;
        #pragma unroll
        for (int w = 0; w < 4; ++w) { int t = wsum[w]; wsum[w] = s; s += t; }
        bsum[blockIdx.x] = s;
    }
    __syncthreads();
    if (i < NN) rowptr[i] = wsum[wid] + x - v;   // block-local exclusive
}

__global__ __launch_bounds__(256) void k_scan_top(int* __restrict__ bsum,
                                                  int* __restrict__ rowptr)
{
    __shared__ int wsum[4];
    const int tid = threadIdx.x, lane = tid & 63, wid = tid >> 6;
    int v = (tid < NB) ? bsum[tid] : 0;
    int x = v;
    #pragma unroll
    for (int off = 1; off < 64; off <<= 1) {
        int t = __shfl_up(x, off);
        if (lane >= off) x += t;
    }
    if (lane == 63) wsum[wid] = x;
    __syncthreads();
    if (tid == 0) {
        int s = 0;
        #pragma unroll
        for (int w = 0; w < 4; ++w) { int t = wsum[w]; wsum[w] = s; s += t; }
    }
    __syncthreads();
    int excl = wsum[wid] + x - v;
    if (tid < NB) bsum[tid] = excl;
    if (tid == NB - 1) rowptr[NN] = excl + v;    // total == NE
}

__global__ __launch_bounds__(256) void k_scan_add(int* __restrict__ rowptr,
                                                  const int* __restrict__ bsum,
                                                  int* __restrict__ cursor)
{
    const int i = blockIdx.x * 256 + threadIdx.x;
    if (i < NN) {
        int r = rowptr[i] + bsum[blockIdx.x];
        rowptr[i] = r;
        cursor[i] = r;
    }
}

// ---------------------------------------------------------------------------
// k_proj: out[mode] = nfeats @ W + (bias if mode 0)
//   mode 0: Wn -> nproj (+bn) ; mode 1: We[0:64] -> Psrc ; mode 2: We[128:192] -> Pdst
// ---------------------------------------------------------------------------
__global__ __launch_bounds__(256) void k_proj(
    const float* __restrict__ nf, const float* __restrict__ Wn,
    const float* __restrict__ bn, const float* __restrict__ We,
    float* __restrict__ nproj, float* __restrict__ Psrc, float* __restrict__ Pdst)
{
    __shared__ __align__(16) float sA[64 * 68];
    __shared__ __align__(16) float sW[64 * 128];
    const int tid = threadIdx.x;
    const int mode = blockIdx.y;
    const int nBase = blockIdx.x * 64;

    const float* W = (mode == 0) ? Wn : (mode == 1 ? We : We + 128 * 128);
    float* outp = (mode == 0) ? nproj : (mode == 1 ? Psrc : Pdst);

    #pragma unroll
    for (int q = 0; q < 4; ++q) {
        int idx = q * 256 + tid;
        int e = idx >> 4, c4 = idx & 15;
        int row = nBase + e;
        float4 v = make_float4(0.f, 0.f, 0.f, 0.f);
        if (row < NN) v = *reinterpret_cast<const float4*>(&nf[row * 64 + c4 * 4]);
        *reinterpret_cast<float4*>(&sA[e * 68 + c4 * 4]) = v;
    }
    #pragma unroll
    for (int q = 0; q < 8; ++q) {
        int idx = q * 256 + tid;
        *reinterpret_cast<float4*>(&sW[idx * 4]) =
            *reinterpret_cast<const float4*>(&W[idx * 4]);
    }
    __syncthreads();

    const int jt = tid & 15, et = tid >> 4;
    float acc[4][8];
    #pragma unroll
    for (int i = 0; i < 4; ++i)
        #pragma unroll
        for (int j = 0; j < 8; ++j) acc[i][j] = 0.f;

    #pragma unroll 2
    for (int kk4 = 0; kk4 < 16; ++kk4) {
        float4 a4[4];
        #pragma unroll
        for (int i = 0; i < 4; ++i)
            a4[i] = *reinterpret_cast<const float4*>(&sA[(4 * et + i) * 68 + 4 * kk4]);
        #pragma unroll
        for (int c = 0; c < 4; ++c) {
            int kk = 4 * kk4 + c;
            float4 b0 = *reinterpret_cast<const float4*>(&sW[kk * 128 + 4 * jt]);
            float4 b1 = *reinterpret_cast<const float4*>(&sW[kk * 128 + 64 + 4 * jt]);
            #pragma unroll
            for (int i = 0; i < 4; ++i) {
                float av = (&a4[i].x)[c];
                acc[i][0] = fmaf(av, b0.x, acc[i][0]);
                acc[i][1] = fmaf(av, b0.y, acc[i][1]);
                acc[i][2] = fmaf(av, b0.z, acc[i][2]);
                acc[i][3] = fmaf(av, b0.w, acc[i][3]);
                acc[i][4] = fmaf(av, b1.x, acc[i][4]);
                acc[i][5] = fmaf(av, b1.y, acc[i][5]);
                acc[i][6] = fmaf(av, b1.z, acc[i][6]);
                acc[i][7] = fmaf(av, b1.w, acc[i][7]);
            }
        }
    }

    float4 bias0 = make_float4(0.f, 0.f, 0.f, 0.f), bias1 = bias0;
    if (mode == 0) {
        bias0 = *reinterpret_cast<const float4*>(&bn[4 * jt]);
        bias1 = *reinterpret_cast<const float4*>(&bn[64 + 4 * jt]);
    }
    #pragma unroll
    for (int i = 0; i < 4; ++i) {
        int row = nBase + 4 * et + i;
        if (row >= NN) continue;
        float4 r0 = make_float4(acc[i][0] + bias0.x, acc[i][1] + bias0.y,
                                acc[i][2] + bias0.z, acc[i][3] + bias0.w);
        float4 r1 = make_float4(acc[i][4] + bias1.x, acc[i][5] + bias1.y,
                                acc[i][6] + bias1.z, acc[i][7] + bias1.w);
        *reinterpret_cast<float4*>(&outp[row * 128 + 4 * jt]) = r0;
        *reinterpret_cast<float4*>(&outp[row * 128 + 64 + 4 * jt]) = r1;
    }
}

// ---------------------------------------------------------------------------
// k_edge: per 64-edge block:
//   prefetch Psrc/Pdst rows into regs (R4, hides L3 latency under GEMM)
//   f = lrelu(ef@We_mid + Psrc[src] + Pdst[dst])   (64x128)
//   a[e][h] = f[e][32h..] . wa_sum ; ex = exp(a)
//   CSR fill: pos = cursor[dst]++ ; srcs[pos]=src ; exs[pos][h]=ex
//   e_out = f @ Woe + boe
// ---------------------------------------------------------------------------
__global__ __launch_bounds__(256, 3) void k_edge(
    const float* __restrict__ ef, const int* __restrict__ src,
    const int* __restrict__ dst, const float* __restrict__ We,
    const float* __restrict__ Wa, const float* __restrict__ Woe,
    const float* __restrict__ boe,
    const float* __restrict__ Psrc, const float* __restrict__ Pdst,
    int* __restrict__ cursor, int* __restrict__ srcs,
    float* __restrict__ exs, float* __restrict__ e_out)
{
    // union: phase A: sA[64*68] | sW[64*128]  (12544 floats)
    //        phase B: sf[64*132] | sWoe[128*32] (12544 floats)
    __shared__ __align__(16) float smem[12544];
    __shared__ __align__(16) int sidx[128];     // src[0..63], dst[64..127]
    __shared__ __align__(16) float swa[32];
    __shared__ __align__(16) float sboe[32];
    __shared__ __align__(16) int spos[64];      // CSR slot per edge

    float* sA = smem;            // [64][68]
    float* sW = smem + 4352;     // [64][128]
    float* sf = smem;            // [64][132]
    float* sWoe = smem + 8448;   // [128][32]

    const int tid = threadIdx.x;
    const int eBase = blockIdx.x * 64;

    // ---- stage ef tile + We_mid + indices + wa_sum + boe ----
    #pragma unroll
    for (int q = 0; q < 4; ++q) {
        int idx = q * 256 + tid;
        int e = idx >> 4, c4 = idx & 15;
        *reinterpret_cast<float4*>(&sA[e * 68 + c4 * 4]) =
            *reinterpret_cast<const float4*>(&ef[(size_t)(eBase + e) * 64 + c4 * 4]);
    }
    #pragma unroll
    for (int q = 0; q < 8; ++q) {
        int idx = q * 256 + tid;
        *reinterpret_cast<float4*>(&sW[idx * 4]) =
            *reinterpret_cast<const float4*>(&We[64 * 128 + idx * 4]);
    }
    if (tid < 64) { sidx[tid] = src[eBase + tid]; sidx[64 + tid] = dst[eBase + tid]; }
    if (tid < 32) {
        float4 w = *reinterpret_cast<const float4*>(&Wa[tid * 4]);
        swa[tid] = w.x + w.y + w.z + w.w;
        sboe[tid] = boe[tid];
    }
    __syncthreads();

    const int jt = tid & 15, et = tid >> 4;

    // ---- R4 prefetch: issue Psrc/Pdst row gathers now, consume after GEMM ----
    float4 ps0[4], ps1[4], pd0[4], pd1[4];
    #pragma unroll
    for (int i = 0; i < 4; ++i) {
        int e = 4 * et + i;
        int s = sidx[e], d = sidx[64 + e];
        ps0[i] = *reinterpret_cast<const float4*>(&Psrc[(size_t)s * 128 + 4 * jt]);
        ps1[i] = *reinterpret_cast<const float4*>(&Psrc[(size_t)s * 128 + 64 + 4 * jt]);
        pd0[i] = *reinterpret_cast<const float4*>(&Pdst[(size_t)d * 128 + 4 * jt]);
        pd1[i] = *reinterpret_cast<const float4*>(&Pdst[(size_t)d * 128 + 64 + 4 * jt]);
    }

    // ---- main GEMM: acc[4e][8j] ----
    float acc[4][8];
    #pragma unroll
    for (int i = 0; i < 4; ++i)
        #pragma unroll
        for (int j = 0; j < 8; ++j) acc[i][j] = 0.f;

    #pragma unroll 2
    for (int kk4 = 0; kk4 < 16; ++kk4) {
        float4 a4[4];
        #pragma unroll
        for (int i = 0; i < 4; ++i)
            a4[i] = *reinterpret_cast<const float4*>(&sA[(4 * et + i) * 68 + 4 * kk4]);
        #pragma unroll
        for (int c = 0; c < 4; ++c) {
            int kk = 4 * kk4 + c;
            float4 b0 = *reinterpret_cast<const float4*>(&sW[kk * 128 + 4 * jt]);
            float4 b1 = *reinterpret_cast<const float4*>(&sW[kk * 128 + 64 + 4 * jt]);
            #pragma unroll
            for (int i = 0; i < 4; ++i) {
                float av = (&a4[i].x)[c];
                acc[i][0] = fmaf(av, b0.x, acc[i][0]);
                acc[i][1] = fmaf(av, b0.y, acc[i][1]);
                acc[i][2] = fmaf(av, b0.z, acc[i][2]);
                acc[i][3] = fmaf(av, b0.w, acc[i][3]);
                acc[i][4] = fmaf(av, b1.x, acc[i][4]);
                acc[i][5] = fmaf(av, b1.y, acc[i][5]);
                acc[i][6] = fmaf(av, b1.z, acc[i][6]);
                acc[i][7] = fmaf(av, b1.w, acc[i][7]);
            }
        }
    }
    __syncthreads();   // sA, sW dead

    // ---- epilogue: f = lrelu(acc + prefetched Psrc/Pdst) -> sf ----
    #pragma unroll
    for (int i = 0; i < 4; ++i) {
        int e = 4 * et + i;
        float4 f0, f1;
        f0.x = lrelu(acc[i][0] + ps0[i].x + pd0[i].x);
        f0.y = lrelu(acc[i][1] + ps0[i].y + pd0[i].y);
        f0.z = lrelu(acc[i][2] + ps0[i].z + pd0[i].z);
        f0.w = lrelu(acc[i][3] + ps0[i].w + pd0[i].w);
        f1.x = lrelu(acc[i][4] + ps1[i].x + pd1[i].x);
        f1.y = lrelu(acc[i][5] + ps1[i].y + pd1[i].y);
        f1.z = lrelu(acc[i][6] + ps1[i].z + pd1[i].z);
        f1.w = lrelu(acc[i][7] + ps1[i].w + pd1[i].w);
        *reinterpret_cast<float4*>(&sf[e * 132 + 4 * jt]) = f0;
        *reinterpret_cast<float4*>(&sf[e * 132 + 64 + 4 * jt]) = f1;
    }
    // stage Woe (sW region is dead, past the barrier)
    #pragma unroll
    for (int q = 0; q < 4; ++q) {
        int idx = q * 256 + tid;
        *reinterpret_cast<float4*>(&sWoe[idx * 4]) =
            *reinterpret_cast<const float4*>(&Woe[idx * 4]);
    }
    __syncthreads();

    // ---- a / ex phase + CSR fill: thread = (e, h) ----
    {
        int e = tid >> 2, h = tid & 3;
        float a = 0.f;
        #pragma unroll
        for (int kk = 0; kk < 8; ++kk) {
            float4 fv = *reinterpret_cast<const float4*>(&sf[e * 132 + h * 32 + kk * 4]);
            float4 wv = *reinterpret_cast<const float4*>(&swa[kk * 4]);
            a = fmaf(fv.x, wv.x, a); a = fmaf(fv.y, wv.y, a);
            a = fmaf(fv.z, wv.z, a); a = fmaf(fv.w, wv.w, a);
        }
        float ex = expf(a);
        int d = sidx[64 + e];
        if (h == 0) spos[e] = atomicAdd(&cursor[d], 1);
        __syncthreads();
        int pos = spos[e];
        exs[(size_t)pos * 4 + h] = ex;
        if (h == 0) srcs[pos] = sidx[e];
    }

    // ---- e_out phase: thread = (e, q), 8 outputs ----
    {
        int e = tid >> 2, q = tid & 3;
        int j0 = q * 8;
        float4 r0 = make_float4(0.f, 0.f, 0.f, 0.f), r1 = r0;
        #pragma unroll 4
        for (int k = 0; k < 128; k += 4) {
            float4 fv = *reinterpret_cast<const float4*>(&sf[e * 132 + k]);
            #pragma unroll
            for (int c = 0; c < 4; ++c) {
                float fk = (&fv.x)[c];
                float4 w0 = *reinterpret_cast<const float4*>(&sWoe[(k + c) * 32 + j0]);
                float4 w1 = *reinterpret_cast<const float4*>(&sWoe[(k + c) * 32 + j0 + 4]);
                r0.x = fmaf(fk, w0.x, r0.x); r0.y = fmaf(fk, w0.y, r0.y);
                r0.z = fmaf(fk, w0.z, r0.z); r0.w = fmaf(fk, w0.w, r0.w);
                r1.x = fmaf(fk, w1.x, r1.x); r1.y = fmaf(fk, w1.y, r1.y);
                r1.z = fmaf(fk, w1.z, r1.z); r1.w = fmaf(fk, w1.w, r1.w);
            }
        }
        float4 b0 = *reinterpret_cast<const float4*>(&sboe[j0]);
        float4 b1 = *reinterpret_cast<const float4*>(&sboe[j0 + 4]);
        r0.x += b0.x; r0.y += b0.y; r0.z += b0.z; r0.w += b0.w;
        r1.x += b1.x; r1.y += b1.y; r1.z += b1.z; r1.w += b1.w;
        size_t o = (size_t)(eBase + e) * 32 + j0;
        *reinterpret_cast<float4*>(&e_out[o]) = r0;
        *reinterpret_cast<float4*>(&e_out[o + 4]) = r1;
    }
}

// ---------------------------------------------------------------------------
// k_agg: per node n (2 nodes/block, 128 threads each, thread owns output j):
//   val = sum_p exs[p][j>>5] * nproj[srcs[p]][j] ; den = sum_p exs[p][j>>5]
//   hbuf[n][j] = deg>0 ? val/den : nproj[n][j]
// ---------------------------------------------------------------------------
__global__ __launch_bounds__(256) void k_agg(
    const int* __restrict__ rowptr, const int* __restrict__ srcs,
    const float* __restrict__ exs, const float* __restrict__ nproj,
    float* __restrict__ hbuf)
{
    const int tid = threadIdx.x;
    const int j = tid & 127;
    const int n = blockIdx.x * 2 + (tid >> 7);
    if (n >= NN) return;
    const int beg = rowptr[n], end = rowptr[n + 1];
    const int h = j >> 5;
    float val = 0.f, den = 0.f;
    int s_next = (beg < end) ? srcs[beg] : 0;
    for (int p = beg; p < end; ++p) {
        int s = s_next;
        if (p + 1 < end) s_next = srcs[p + 1];
        float ex = exs[(size_t)p * 4 + h];
        val = fmaf(ex, nproj[(size_t)s * 128 + j], val);
        den += ex;
    }
    float out = (end > beg) ? (val / den) : nproj[(size_t)n * 128 + j];
    hbuf[(size_t)n * 128 + j] = out;
}

// ---------------------------------------------------------------------------
// k_node_out: h_out = hbuf @ Won + bon
// ---------------------------------------------------------------------------
__global__ __launch_bounds__(256) void k_node_out(
    const float* __restrict__ hbuf, const float* __restrict__ Won,
    const float* __restrict__ bon, float* __restrict__ h_out)
{
    __shared__ __align__(16) float sh[64 * 132];
    __shared__ __align__(16) float sWon[128 * 32];
    __shared__ __align__(16) float sbon[32];
    const int tid = threadIdx.x;
    const int nBase = blockIdx.x * 64;

    #pragma unroll
    for (int q = 0; q < 8; ++q) {
        int idx = q * 256 + tid;
        int n = idx >> 5, c4 = idx & 31;
        int row = nBase + n;
        float4 v = make_float4(0.f, 0.f, 0.f, 0.f);
        if (row < NN)
            v = *reinterpret_cast<const float4*>(&hbuf[(size_t)row * 128 + c4 * 4]);
        *reinterpret_cast<float4*>(&sh[n * 132 + c4 * 4]) = v;
    }
    #pragma unroll
    for (int q = 0; q < 4; ++q) {
        int idx = q * 256 + tid;
        *reinterpret_cast<float4*>(&sWon[idx * 4]) =
            *reinterpret_cast<const float4*>(&Won[idx * 4]);
    }
    if (tid < 32) sbon[tid] = bon[tid];
    __syncthreads();

    int n = tid >> 2, q = tid & 3;
    int j0 = q * 8;
    int row = nBase + n;
    float4 r0 = make_float4(0.f, 0.f, 0.f, 0.f), r1 = r0;
    #pragma unroll 4
    for (int k = 0; k < 128; k += 4) {
        float4 fv = *reinterpret_cast<const float4*>(&sh[n * 132 + k]);
        #pragma unroll
        for (int c = 0; c < 4; ++c) {
            float fk = (&fv.x)[c];
            float4 w0 = *reinterpret_cast<const float4*>(&sWon[(k + c) * 32 + j0]);
            float4 w1 = *reinterpret_cast<const float4*>(&sWon[(k + c) * 32 + j0 + 4]);
            r0.x = fmaf(fk, w0.x, r0.x); r0.y = fmaf(fk, w0.y, r0.y);
            r0.z = fmaf(fk, w0.z, r0.z); r0.w = fmaf(fk, w0.w, r0.w);
            r1.x = fmaf(fk, w1.x, r1.x); r1.y = fmaf(fk, w1.y, r1.y);
            r1.z = fmaf(fk, w1.z, r1.z); r1.w = fmaf(fk, w1.w, r1.w);
        }
    }
    if (row < NN) {
        float4 b0 = *reinterpret_cast<const float4*>(&sbon[j0]);
        float4 b1 = *reinterpret_cast<const float4*>(&sbon[j0 + 4]);
        r0.x += b0.x; r0.y += b0.y; r0.z += b0.z; r0.w += b0.w;
        r1.x += b1.x; r1.y += b1.y; r1.z += b1.z; r1.w += b1.w;
        size_t o = (size_t)row * 32 + j0;
        *reinterpret_cast<float4*>(&h_out[o]) = r0;
        *reinterpret_cast<float4*>(&h_out[o + 4]) = r1;
    }
}

extern "C" void kernel_launch(void* const* d_in, const int* in_sizes, int n_in,
                              void* d_out, int out_size, void* d_ws, size_t ws_size,
                              hipStream_t stream) {
    const float* nfeats = (const float*)d_in[0];
    const float* efeats = (const float*)d_in[1];
    const int*   src    = (const int*)d_in[2];
    const int*   dst    = (const int*)d_in[3];
    const float* Wn     = (const float*)d_in[4];
    const float* bn     = (const float*)d_in[5];
    const float* We     = (const float*)d_in[6];
    const float* Wa     = (const float*)d_in[7];
    const float* Won    = (const float*)d_in[8];
    const float* bon    = (const float*)d_in[9];
    const float* Woe    = (const float*)d_in[10];
    const float* boe    = (const float*)d_in[11];

    float* h_out = (float*)d_out;                 // [N,32]
    float* e_out = h_out + (size_t)NN * 32;       // [E,32]

    // ws layout: nproj[N*128]f | Psrc[N*128]f (hbuf aliases after k_edge) |
    //            Pdst[N*128]f | exs[E*4]f | deg[N]i | rowptr[N+1]i |
    //            cursor[N]i | srcs[E]i | bsum[256]i   (~93 MB total)
    float* nproj  = (float*)d_ws;
    float* Psrc   = nproj + (size_t)NN * 128;
    float* Pdst   = Psrc + (size_t)NN * 128;
    float* exs    = Pdst + (size_t)NN * 128;
    int*   deg    = (int*)(exs + (size_t)NE * 4);
    int*   rowptr = deg + NN;
    int*   cursor = rowptr + NN + 1;
    int*   srcs   = cursor + NN;
    int*   bsum   = srcs + NE;
    float* hbuf   = Psrc;                         // Psrc dead after k_edge

    hipMemsetAsync(deg, 0, NN * sizeof(int), stream);

    k_count<<<1024, 256, 0, stream>>>(dst, deg);
    k_scan_blk<<<NB, 256, 0, stream>>>(deg, rowptr, bsum);
    k_scan_top<<<1, 256, 0, stream>>>(bsum, rowptr);
    k_scan_add<<<NB, 256, 0, stream>>>(rowptr, bsum, cursor);

    dim3 gProj((NN + 63) / 64, 3);
    k_proj<<<gProj, 256, 0, stream>>>(nfeats, Wn, bn, We, nproj, Psrc, Pdst);

    k_edge<<<NE / 64, 256, 0, stream>>>(efeats, src, dst, We, Wa, Woe, boe,
                                        Psrc, Pdst, cursor, srcs, exs, e_out);

    k_agg<<<(NN + 1) / 2, 256, 0, stream>>>(rowptr, srcs, exs, nproj, hbuf);

    k_node_out<<<(NN + 63) / 64, 256, 0, stream>>>(hbuf, Won, bon, h_out);
}

// Round 8
// 779.656 us; speedup vs baseline: 2.2312x; 1.0395x over previous
//
#include <hip/hip_runtime.h>
#include <hip/hip_bf16.h>

// EGATConv fused forward, MI355X.
// R3: dst-CSR replaced 102.4M f32 atomics (k_edge 1451->343us).
// R4: parallel scan; reg-prefetch FAILED (compiler sank loads, VGPR stayed 80).
// R5: main edge GEMM -> bf16 MFMA (16x16x32). A-frags cvt'd from global ef,
//     B-frags precomputed lane-linear by k_prepw (L2-resident); softmax 'a'
//     wave-parallel via shfl_xor from the MFMA accumulator.
// R6 FIX: epilogue read wa_sum[j] with j in [0,128) but wa_sum has 32 entries
//     (a = f . rowsum(Wa) contracts over fo = j&31 within each head j>>5).
//     OOB read pulled Wefrag bytes -> absmax 7.6e-2. Now wa_sum[j & 31].
// R7: resubmit of R6 (GPU acquisition timed out; fix never measured).
// Algebra: stack@We = Psrc[src] + ef@We_mid + Pdst[dst]; a = f . rowsum(Wa);
// softmax max-shift skipped (|a|~0.3); normalization folded to node level.

#define NN 50000
#define NE 800000
#define NB ((NN + 255) / 256)   // 196 scan blocks

typedef __attribute__((ext_vector_type(8))) __bf16 bf16x8;
typedef __attribute__((ext_vector_type(4))) float f32x4;

__device__ __forceinline__ float lrelu(float x) { return x > 0.f ? x : 0.01f * x; }

// ---------------------------------------------------------------------------
// k_count: deg[n] = #edges with dst==n
// ---------------------------------------------------------------------------
__global__ __launch_bounds__(256) void k_count(const int* __restrict__ dst,
                                               int* __restrict__ deg)
{
    int i = blockIdx.x * blockDim.x + threadIdx.x;
    int stride = gridDim.x * blockDim.x;
    for (; i < NE; i += stride) atomicAdd(&deg[dst[i]], 1);
}

// ---------------------------------------------------------------------------
// 3-kernel exclusive scan of deg[NN] -> rowptr/cursor
// ---------------------------------------------------------------------------
__global__ __launch_bounds__(256) void k_scan_blk(const int* __restrict__ deg,
                                                  int* __restrict__ rowptr,
                                                  int* __restrict__ bsum)
{
    __shared__ int wsum[4];
    const int tid = threadIdx.x, lane = tid & 63, wid = tid >> 6;
    const int i = blockIdx.x * 256 + tid;
    int v = (i < NN) ? deg[i] : 0;
    int x = v;
    #pragma unroll
    for (int off = 1; off < 64; off <<= 1) {
        int t = __shfl_up(x, off);
        if (lane >= off) x += t;
    }
    if (lane == 63) wsum[wid] = x;
    __syncthreads();
    if (tid == 0) {
        int s = 0;
        #pragma unroll
        for (int w = 0; w < 4; ++w) { int t = wsum[w]; wsum[w] = s; s += t; }
        bsum[blockIdx.x] = s;
    }
    __syncthreads();
    if (i < NN) rowptr[i] = wsum[wid] + x - v;   // block-local exclusive
}

__global__ __launch_bounds__(256) void k_scan_top(int* __restrict__ bsum,
                                                  int* __restrict__ rowptr)
{
    __shared__ int wsum[4];
    const int tid = threadIdx.x, lane = tid & 63, wid = tid >> 6;
    int v = (tid < NB) ? bsum[tid] : 0;
    int x = v;
    #pragma unroll
    for (int off = 1; off < 64; off <<= 1) {
        int t = __shfl_up(x, off);
        if (lane >= off) x += t;
    }
    if (lane == 63) wsum[wid] = x;
    __syncthreads();
    if (tid == 0) {
        int s = 0;
        #pragma unroll
        for (int w = 0; w < 4; ++w) { int t = wsum[w]; wsum[w] = s; s += t; }
    }
    __syncthreads();
    int excl = wsum[wid] + x - v;
    if (tid < NB) bsum[tid] = excl;
    if (tid == NB - 1) rowptr[NN] = excl + v;    // total == NE
}

__global__ __launch_bounds__(256) void k_scan_add(int* __restrict__ rowptr,
                                                  const int* __restrict__ bsum,
                                                  int* __restrict__ cursor)
{
    const int i = blockIdx.x * 256 + threadIdx.x;
    if (i < NN) {
        int r = rowptr[i] + bsum[blockIdx.x];
        rowptr[i] = r;
        cursor[i] = r;
    }
}

// ---------------------------------------------------------------------------
// k_prepw: build lane-linear bf16 B-fragment table for We_mid + wa_sum.
// Wefrag[((t*2+h)*64 + lane)*8 + j] = bf16(We[(64 + 32h + (lane>>4)*8 + j)*128
//                                            + 16t + (lane&15)])
// ---------------------------------------------------------------------------
__global__ __launch_bounds__(256) void k_prepw(const float* __restrict__ We,
                                               const float* __restrict__ Wa,
                                               unsigned short* __restrict__ Wefrag,
                                               float* __restrict__ wa_sum)
{
    const int tid = threadIdx.x;
    if (tid < 32) {
        float4 w = *reinterpret_cast<const float4*>(&Wa[tid * 4]);
        wa_sum[tid] = w.x + w.y + w.z + w.w;
    }
    #pragma unroll
    for (int i = 0; i < 32; ++i) {
        int idx = tid * 32 + i;                  // 8192 entries
        int j = idx & 7, l = (idx >> 3) & 63, th = idx >> 9;
        int h = th & 1, t = th >> 1;
        int k = 32 * h + (l >> 4) * 8 + j;
        int c = 16 * t + (l & 15);
        __bf16 b = (__bf16)We[(64 + k) * 128 + c];
        Wefrag[idx] = *reinterpret_cast<unsigned short*>(&b);
    }
}

// ---------------------------------------------------------------------------
// k_proj: out[mode] = nfeats @ W + (bias if mode 0)  (f32 vector GEMM)
// ---------------------------------------------------------------------------
__global__ __launch_bounds__(256) void k_proj(
    const float* __restrict__ nf, const float* __restrict__ Wn,
    const float* __restrict__ bn, const float* __restrict__ We,
    float* __restrict__ nproj, float* __restrict__ Psrc, float* __restrict__ Pdst)
{
    __shared__ __align__(16) float sA[64 * 68];
    __shared__ __align__(16) float sW[64 * 128];
    const int tid = threadIdx.x;
    const int mode = blockIdx.y;
    const int nBase = blockIdx.x * 64;

    const float* W = (mode == 0) ? Wn : (mode == 1 ? We : We + 128 * 128);
    float* outp = (mode == 0) ? nproj : (mode == 1 ? Psrc : Pdst);

    #pragma unroll
    for (int q = 0; q < 4; ++q) {
        int idx = q * 256 + tid;
        int e = idx >> 4, c4 = idx & 15;
        int row = nBase + e;
        float4 v = make_float4(0.f, 0.f, 0.f, 0.f);
        if (row < NN) v = *reinterpret_cast<const float4*>(&nf[row * 64 + c4 * 4]);
        *reinterpret_cast<float4*>(&sA[e * 68 + c4 * 4]) = v;
    }
    #pragma unroll
    for (int q = 0; q < 8; ++q) {
        int idx = q * 256 + tid;
        *reinterpret_cast<float4*>(&sW[idx * 4]) =
            *reinterpret_cast<const float4*>(&W[idx * 4]);
    }
    __syncthreads();

    const int jt = tid & 15, et = tid >> 4;
    float acc[4][8];
    #pragma unroll
    for (int i = 0; i < 4; ++i)
        #pragma unroll
        for (int j = 0; j < 8; ++j) acc[i][j] = 0.f;

    #pragma unroll 2
    for (int kk4 = 0; kk4 < 16; ++kk4) {
        float4 a4[4];
        #pragma unroll
        for (int i = 0; i < 4; ++i)
            a4[i] = *reinterpret_cast<const float4*>(&sA[(4 * et + i) * 68 + 4 * kk4]);
        #pragma unroll
        for (int c = 0; c < 4; ++c) {
            int kk = 4 * kk4 + c;
            float4 b0 = *reinterpret_cast<const float4*>(&sW[kk * 128 + 4 * jt]);
            float4 b1 = *reinterpret_cast<const float4*>(&sW[kk * 128 + 64 + 4 * jt]);
            #pragma unroll
            for (int i = 0; i < 4; ++i) {
                float av = (&a4[i].x)[c];
                acc[i][0] = fmaf(av, b0.x, acc[i][0]);
                acc[i][1] = fmaf(av, b0.y, acc[i][1]);
                acc[i][2] = fmaf(av, b0.z, acc[i][2]);
                acc[i][3] = fmaf(av, b0.w, acc[i][3]);
                acc[i][4] = fmaf(av, b1.x, acc[i][4]);
                acc[i][5] = fmaf(av, b1.y, acc[i][5]);
                acc[i][6] = fmaf(av, b1.z, acc[i][6]);
                acc[i][7] = fmaf(av, b1.w, acc[i][7]);
            }
        }
    }

    float4 bias0 = make_float4(0.f, 0.f, 0.f, 0.f), bias1 = bias0;
    if (mode == 0) {
        bias0 = *reinterpret_cast<const float4*>(&bn[4 * jt]);
        bias1 = *reinterpret_cast<const float4*>(&bn[64 + 4 * jt]);
    }
    #pragma unroll
    for (int i = 0; i < 4; ++i) {
        int row = nBase + 4 * et + i;
        if (row >= NN) continue;
        float4 r0 = make_float4(acc[i][0] + bias0.x, acc[i][1] + bias0.y,
                                acc[i][2] + bias0.z, acc[i][3] + bias0.w);
        float4 r1 = make_float4(acc[i][4] + bias1.x, acc[i][5] + bias1.y,
                                acc[i][6] + bias1.z, acc[i][7] + bias1.w);
        *reinterpret_cast<float4*>(&outp[row * 128 + 4 * jt]) = r0;
        *reinterpret_cast<float4*>(&outp[row * 128 + 64 + 4 * jt]) = r1;
    }
}

// ---------------------------------------------------------------------------
// k_edge: 64 edges/block, 4 waves, wave w owns rows 16w..16w+15.
//   MFMA main GEMM: acc[t] (t = 8 col-tiles), A from global ef (cvt bf16),
//   B from Wefrag table. C layout: col = 16t+(l&15), row = 4*(l>>4)+reg.
//   Epilogue: f = lrelu(acc + Psrc + Pdst) -> sf (f32), a-dot via shfl_xor,
//   ex/CSR fill. Then barrier, e_out = f@Woe f32 from sf/sWoe.
// ---------------------------------------------------------------------------
__global__ __launch_bounds__(256) void k_edge(
    const float* __restrict__ ef, const int* __restrict__ src,
    const int* __restrict__ dst,
    const unsigned short* __restrict__ Wefrag, const float* __restrict__ wa_sum,
    const float* __restrict__ Woe, const float* __restrict__ boe,
    const float* __restrict__ Psrc, const float* __restrict__ Pdst,
    int* __restrict__ cursor, int* __restrict__ srcs,
    float* __restrict__ exs, float* __restrict__ e_out)
{
    __shared__ __align__(16) float sf[64 * 132];
    __shared__ __align__(16) float sWoe[128 * 32];
    __shared__ __align__(16) float sboe[32];

    const int tid = threadIdx.x;
    const int w = tid >> 6, l = tid & 63;
    const int g = l >> 4, c16 = l & 15;
    const int eBase = blockIdx.x * 64;
    const int rowBase = eBase + 16 * w;

    // stage Woe + boe (consumed after the barrier)
    #pragma unroll
    for (int q = 0; q < 4; ++q) {
        int idx = q * 256 + tid;
        *reinterpret_cast<float4*>(&sWoe[idx * 4]) =
            *reinterpret_cast<const float4*>(&Woe[idx * 4]);
    }
    if (tid < 32) sboe[tid] = boe[tid];

    // src/dst for this group's 4 rows (broadcast loads, L2-hot)
    int sreg[4], dreg[4];
    #pragma unroll
    for (int r = 0; r < 4; ++r) {
        sreg[r] = src[rowBase + 4 * g + r];
        dreg[r] = dst[rowBase + 4 * g + r];
    }

    // A fragments: row = c16, k = 32h + 8g + j  (8 consecutive f32 -> bf16x8)
    bf16x8 afrag[2];
    #pragma unroll
    for (int h = 0; h < 2; ++h) {
        const float* ap = &ef[(size_t)(rowBase + c16) * 64 + 32 * h + 8 * g];
        float4 a0 = *reinterpret_cast<const float4*>(ap);
        float4 a1 = *reinterpret_cast<const float4*>(ap + 4);
        bf16x8 v;
        v[0] = (__bf16)a0.x; v[1] = (__bf16)a0.y;
        v[2] = (__bf16)a0.z; v[3] = (__bf16)a0.w;
        v[4] = (__bf16)a1.x; v[5] = (__bf16)a1.y;
        v[6] = (__bf16)a1.z; v[7] = (__bf16)a1.w;
        afrag[h] = v;
    }

    // MFMA: 8 col-tiles x 2 K-halves
    f32x4 acc[8];
    #pragma unroll
    for (int t = 0; t < 8; ++t) {
        f32x4 z = {0.f, 0.f, 0.f, 0.f};
        acc[t] = z;
        #pragma unroll
        for (int h = 0; h < 2; ++h) {
            bf16x8 b = *reinterpret_cast<const bf16x8*>(
                &Wefrag[((size_t)(t * 2 + h) * 64 + l) * 8]);
            acc[t] = __builtin_amdgcn_mfma_f32_16x16x32_bf16(afrag[h], b, acc[t], 0, 0, 0);
        }
    }

    // epilogue: f = lrelu(acc + Psrc + Pdst); write sf; accumulate a partials
    float a_acc[4][4];                    // [reg][head]
    #pragma unroll
    for (int r = 0; r < 4; ++r)
        #pragma unroll
        for (int h = 0; h < 4; ++h) a_acc[r][h] = 0.f;

    #pragma unroll
    for (int t = 0; t < 8; ++t) {
        int j = 16 * t + c16;
        float waj = wa_sum[j & 31];       // R6 fix: rowsum(Wa) indexed by fo = j mod 32
        #pragma unroll
        for (int r = 0; r < 4; ++r) {
            float ps = Psrc[(size_t)sreg[r] * 128 + j];
            float pd = Pdst[(size_t)dreg[r] * 128 + j];
            float f = lrelu(acc[t][r] + ps + pd);
            sf[(16 * w + 4 * g + r) * 132 + j] = f;
            a_acc[r][t >> 1] = fmaf(f, waj, a_acc[r][t >> 1]);
        }
    }

    // reduce a over the 16-lane group (cols of the head covered across lanes)
    #pragma unroll
    for (int r = 0; r < 4; ++r)
        #pragma unroll
        for (int h = 0; h < 4; ++h) {
            float v = a_acc[r][h];
            v += __shfl_xor(v, 1);
            v += __shfl_xor(v, 2);
            v += __shfl_xor(v, 4);
            v += __shfl_xor(v, 8);
            a_acc[r][h] = v;
        }

    // CSR fill: one atomic per row; lanes c16<4 write the 4 head ex values
    #pragma unroll
    for (int r = 0; r < 4; ++r) {
        int pos = 0;
        if (c16 == 0) pos = atomicAdd(&cursor[dreg[r]], 1);
        pos = __shfl(pos, g * 16);
        if (c16 == 0) srcs[pos] = sreg[r];
        float ex = expf(a_acc[r][c16 & 3]);
        if (c16 < 4) exs[(size_t)pos * 4 + c16] = ex;
    }

    __syncthreads();   // sf + sWoe ready

    // e_out = f @ Woe + boe : thread = (e, q), 8 outputs, f32 vector
    {
        int e = tid >> 2, q = tid & 3;
        int j0 = q * 8;
        float4 r0 = make_float4(0.f, 0.f, 0.f, 0.f), r1 = r0;
        #pragma unroll 4
        for (int k = 0; k < 128; k += 4) {
            float4 fv = *reinterpret_cast<const float4*>(&sf[e * 132 + k]);
            #pragma unroll
            for (int c = 0; c < 4; ++c) {
                float fk = (&fv.x)[c];
                float4 w0 = *reinterpret_cast<const float4*>(&sWoe[(k + c) * 32 + j0]);
                float4 w1 = *reinterpret_cast<const float4*>(&sWoe[(k + c) * 32 + j0 + 4]);
                r0.x = fmaf(fk, w0.x, r0.x); r0.y = fmaf(fk, w0.y, r0.y);
                r0.z = fmaf(fk, w0.z, r0.z); r0.w = fmaf(fk, w0.w, r0.w);
                r1.x = fmaf(fk, w1.x, r1.x); r1.y = fmaf(fk, w1.y, r1.y);
                r1.z = fmaf(fk, w1.z, r1.z); r1.w = fmaf(fk, w1.w, r1.w);
            }
        }
        float4 b0 = *reinterpret_cast<const float4*>(&sboe[j0]);
        float4 b1 = *reinterpret_cast<const float4*>(&sboe[j0 + 4]);
        r0.x += b0.x; r0.y += b0.y; r0.z += b0.z; r0.w += b0.w;
        r1.x += b1.x; r1.y += b1.y; r1.z += b1.z; r1.w += b1.w;
        size_t o = (size_t)(eBase + e) * 32 + j0;
        *reinterpret_cast<float4*>(&e_out[o]) = r0;
        *reinterpret_cast<float4*>(&e_out[o + 4]) = r1;
    }
}

// ---------------------------------------------------------------------------
// k_agg: per node n (2 nodes/block, 128 threads each, thread owns output j)
// ---------------------------------------------------------------------------
__global__ __launch_bounds__(256) void k_agg(
    const int* __restrict__ rowptr, const int* __restrict__ srcs,
    const float* __restrict__ exs, const float* __restrict__ nproj,
    float* __restrict__ hbuf)
{
    const int tid = threadIdx.x;
    const int j = tid & 127;
    const int n = blockIdx.x * 2 + (tid >> 7);
    if (n >= NN) return;
    const int beg = rowptr[n], end = rowptr[n + 1];
    const int h = j >> 5;
    float val = 0.f, den = 0.f;
    int s_next = (beg < end) ? srcs[beg] : 0;
    for (int p = beg; p < end; ++p) {
        int s = s_next;
        if (p + 1 < end) s_next = srcs[p + 1];
        float ex = exs[(size_t)p * 4 + h];
        val = fmaf(ex, nproj[(size_t)s * 128 + j], val);
        den += ex;
    }
    float out = (end > beg) ? (val / den) : nproj[(size_t)n * 128 + j];
    hbuf[(size_t)n * 128 + j] = out;
}

// ---------------------------------------------------------------------------
// k_node_out: h_out = hbuf @ Won + bon
// ---------------------------------------------------------------------------
__global__ __launch_bounds__(256) void k_node_out(
    const float* __restrict__ hbuf, const float* __restrict__ Won,
    const float* __restrict__ bon, float* __restrict__ h_out)
{
    __shared__ __align__(16) float sh[64 * 132];
    __shared__ __align__(16) float sWon[128 * 32];
    __shared__ __align__(16) float sbon[32];
    const int tid = threadIdx.x;
    const int nBase = blockIdx.x * 64;

    #pragma unroll
    for (int q = 0; q < 8; ++q) {
        int idx = q * 256 + tid;
        int n = idx >> 5, c4 = idx & 31;
        int row = nBase + n;
        float4 v = make_float4(0.f, 0.f, 0.f, 0.f);
        if (row < NN)
            v = *reinterpret_cast<const float4*>(&hbuf[(size_t)row * 128 + c4 * 4]);
        *reinterpret_cast<float4*>(&sh[n * 132 + c4 * 4]) = v;
    }
    #pragma unroll
    for (int q = 0; q < 4; ++q) {
        int idx = q * 256 + tid;
        *reinterpret_cast<float4*>(&sWon[idx * 4]) =
            *reinterpret_cast<const float4*>(&Won[idx * 4]);
    }
    if (tid < 32) sbon[tid] = bon[tid];
    __syncthreads();

    int n = tid >> 2, q = tid & 3;
    int j0 = q * 8;
    int row = nBase + n;
    float4 r0 = make_float4(0.f, 0.f, 0.f, 0.f), r1 = r0;
    #pragma unroll 4
    for (int k = 0; k < 128; k += 4) {
        float4 fv = *reinterpret_cast<const float4*>(&sh[n * 132 + k]);
        #pragma unroll
        for (int c = 0; c < 4; ++c) {
            float fk = (&fv.x)[c];
            float4 w0 = *reinterpret_cast<const float4*>(&sWon[(k + c) * 32 + j0]);
            float4 w1 = *reinterpret_cast<const float4*>(&sWon[(k + c) * 32 + j0 + 4]);
            r0.x = fmaf(fk, w0.x, r0.x); r0.y = fmaf(fk, w0.y, r0.y);
            r0.z = fmaf(fk, w0.z, r0.z); r0.w = fmaf(fk, w0.w, r0.w);
            r1.x = fmaf(fk, w1.x, r1.x); r1.y = fmaf(fk, w1.y, r1.y);
            r1.z = fmaf(fk, w1.z, r1.z); r1.w = fmaf(fk, w1.w, r1.w);
        }
    }
    if (row < NN) {
        float4 b0 = *reinterpret_cast<const float4*>(&sbon[j0]);
        float4 b1 = *reinterpret_cast<const float4*>(&sbon[j0 + 4]);
        r0.x += b0.x; r0.y += b0.y; r0.z += b0.z; r0.w += b0.w;
        r1.x += b1.x; r1.y += b1.y; r1.z += b1.z; r1.w += b1.w;
        size_t o = (size_t)row * 32 + j0;
        *reinterpret_cast<float4*>(&h_out[o]) = r0;
        *reinterpret_cast<float4*>(&h_out[o + 4]) = r1;
    }
}

extern "C" void kernel_launch(void* const* d_in, const int* in_sizes, int n_in,
                              void* d_out, int out_size, void* d_ws, size_t ws_size,
                              hipStream_t stream) {
    const float* nfeats = (const float*)d_in[0];
    const float* efeats = (const float*)d_in[1];
    const int*   src    = (const int*)d_in[2];
    const int*   dst    = (const int*)d_in[3];
    const float* Wn     = (const float*)d_in[4];
    const float* bn     = (const float*)d_in[5];
    const float* We     = (const float*)d_in[6];
    const float* Wa     = (const float*)d_in[7];
    const float* Won    = (const float*)d_in[8];
    const float* bon    = (const float*)d_in[9];
    const float* Woe    = (const float*)d_in[10];
    const float* boe    = (const float*)d_in[11];

    float* h_out = (float*)d_out;                 // [N,32]
    float* e_out = h_out + (size_t)NN * 32;       // [E,32]

    // ws layout: nproj[N*128]f | Psrc[N*128]f (hbuf aliases after k_edge) |
    //   Pdst[N*128]f | exs[E*4]f | deg[N]i | rowptr[N+1]i | cursor[N]i |
    //   srcs[E]i | bsum[256]i | wa_sum[32]f | Wefrag[8192]u16 (16B-aligned)
    float* nproj  = (float*)d_ws;
    float* Psrc   = nproj + (size_t)NN * 128;
    float* Pdst   = Psrc + (size_t)NN * 128;
    float* exs    = Pdst + (size_t)NN * 128;
    int*   deg    = (int*)(exs + (size_t)NE * 4);
    int*   rowptr = deg + NN;
    int*   cursor = rowptr + NN + 1;
    int*   srcs   = cursor + NN;
    int*   bsum   = srcs + NE;
    float* wa_sum = (float*)(bsum + 256);
    unsigned short* Wefrag =
        (unsigned short*)(((uintptr_t)(wa_sum + 32) + 15) & ~(uintptr_t)15);
    float* hbuf   = Psrc;                         // Psrc dead after k_edge

    hipMemsetAsync(deg, 0, NN * sizeof(int), stream);

    k_count<<<1024, 256, 0, stream>>>(dst, deg);
    k_scan_blk<<<NB, 256, 0, stream>>>(deg, rowptr, bsum);
    k_scan_top<<<1, 256, 0, stream>>>(bsum, rowptr);
    k_scan_add<<<NB, 256, 0, stream>>>(rowptr, bsum, cursor);

    k_prepw<<<1, 256, 0, stream>>>(We, Wa, Wefrag, wa_sum);

    dim3 gProj((NN + 63) / 64, 3);
    k_proj<<<gProj, 256, 0, stream>>>(nfeats, Wn, bn, We, nproj, Psrc, Pdst);

    k_edge<<<NE / 64, 256, 0, stream>>>(efeats, src, dst, Wefrag, wa_sum,
                                        Woe, boe, Psrc, Pdst,
                                        cursor, srcs, exs, e_out);

    k_agg<<<(NN + 1) / 2, 256, 0, stream>>>(rowptr, srcs, exs, nproj, hbuf);

    k_node_out<<<(NN + 63) / 64, 256, 0, stream>>>(hbuf, Won, bon, h_out);
}

// Round 9
// 708.418 us; speedup vs baseline: 2.4556x; 1.1006x over previous
//
#include <hip/hip_runtime.h>
#include <hip/hip_bf16.h>

// EGATConv fused forward, MI355X.
// R3: dst-CSR replaced 102.4M f32 atomics (k_edge 1451->343us).
// R4: parallel scan; reg-prefetch FAILED (compiler sank loads).
// R5/R6: main edge GEMM -> bf16 MFMA (verified R8: pass, absmax 0.0078).
// R8 profile: k_edge 352us with VALU 27% / MFMA 1.5% / HBM 24% / Occ 21%
//   -> LATENCY-bound on the Psrc/Pdst gather (64 scalar 4B loads/thread)
//   at 3 blocks/CU (50.7KB LDS).
// R9: (a) epilogue re-mapped to thread=(edge,quarter): gather as 16 float4
//     (64B segs) via in-place bf16 LDS bounce fbuf[64][136];
//     (b) e_out -> MFMA (A-frags from fbuf b128, B from Woefrag table);
//     sWoe/sf-f32 staging dropped: LDS 50.7->18KB (occupancy 3->5 blk/CU).
// Algebra: stack@We = Psrc[src] + ef@We_mid + Pdst[dst]; a = f . rowsum(Wa);
// softmax max-shift skipped (|a|~0.3); normalization folded to node level.

#define NN 50000
#define NE 800000
#define NB ((NN + 255) / 256)   // 196 scan blocks

typedef __attribute__((ext_vector_type(8))) __bf16 bf16x8;
typedef __attribute__((ext_vector_type(4))) float f32x4;

__device__ __forceinline__ float lrelu(float x) { return x > 0.f ? x : 0.01f * x; }
__device__ __forceinline__ unsigned short f2bf(float x) {
    __bf16 b = (__bf16)x; return *reinterpret_cast<unsigned short*>(&b);
}
__device__ __forceinline__ float bf2f(unsigned short u) {
    __bf16 b = *reinterpret_cast<__bf16*>(&u); return (float)b;
}

// ---------------------------------------------------------------------------
// k_count: deg[n] = #edges with dst==n
// ---------------------------------------------------------------------------
__global__ __launch_bounds__(256) void k_count(const int* __restrict__ dst,
                                               int* __restrict__ deg)
{
    int i = blockIdx.x * blockDim.x + threadIdx.x;
    int stride = gridDim.x * blockDim.x;
    for (; i < NE; i += stride) atomicAdd(&deg[dst[i]], 1);
}

// ---------------------------------------------------------------------------
// 3-kernel exclusive scan of deg[NN] -> rowptr/cursor
// ---------------------------------------------------------------------------
__global__ __launch_bounds__(256) void k_scan_blk(const int* __restrict__ deg,
                                                  int* __restrict__ rowptr,
                                                  int* __restrict__ bsum)
{
    __shared__ int wsum[4];
    const int tid = threadIdx.x, lane = tid & 63, wid = tid >> 6;
    const int i = blockIdx.x * 256 + tid;
    int v = (i < NN) ? deg[i] : 0;
    int x = v;
    #pragma unroll
    for (int off = 1; off < 64; off <<= 1) {
        int t = __shfl_up(x, off);
        if (lane >= off) x += t;
    }
    if (lane == 63) wsum[wid] = x;
    __syncthreads();
    if (tid == 0) {
        int s = 0;
        #pragma unroll
        for (int w = 0; w < 4; ++w) { int t = wsum[w]; wsum[w] = s; s += t; }
        bsum[blockIdx.x] = s;
    }
    __syncthreads();
    if (i < NN) rowptr[i] = wsum[wid] + x - v;   // block-local exclusive
}

__global__ __launch_bounds__(256) void k_scan_top(int* __restrict__ bsum,
                                                  int* __restrict__ rowptr)
{
    __shared__ int wsum[4];
    const int tid = threadIdx.x, lane = tid & 63, wid = tid >> 6;
    int v = (tid < NB) ? bsum[tid] : 0;
    int x = v;
    #pragma unroll
    for (int off = 1; off < 64; off <<= 1) {
        int t = __shfl_up(x, off);
        if (lane >= off) x += t;
    }
    if (lane == 63) wsum[wid] = x;
    __syncthreads();
    if (tid == 0) {
        int s = 0;
        #pragma unroll
        for (int w = 0; w < 4; ++w) { int t = wsum[w]; wsum[w] = s; s += t; }
    }
    __syncthreads();
    int excl = wsum[wid] + x - v;
    if (tid < NB) bsum[tid] = excl;
    if (tid == NB - 1) rowptr[NN] = excl + v;    // total == NE
}

__global__ __launch_bounds__(256) void k_scan_add(int* __restrict__ rowptr,
                                                  const int* __restrict__ bsum,
                                                  int* __restrict__ cursor)
{
    const int i = blockIdx.x * 256 + threadIdx.x;
    if (i < NN) {
        int r = rowptr[i] + bsum[blockIdx.x];
        rowptr[i] = r;
        cursor[i] = r;
    }
}

// ---------------------------------------------------------------------------
// k_prepw: bf16 B-fragment tables (We_mid -> Wefrag, Woe -> Woefrag) + wa_sum.
// Wefrag[((t*2+h)*64+l)*8+j]  = bf16(We[(64 + 32h + 8*(l>>4) + j)*128 + 16t + (l&15)])
// Woefrag[((u*4+ks)*64+l)*8+j] = bf16(Woe[(32ks + 8*(l>>4) + j)*32 + 16u + (l&15)])
// ---------------------------------------------------------------------------
__global__ __launch_bounds__(256) void k_prepw(const float* __restrict__ We,
                                               const float* __restrict__ Wa,
                                               const float* __restrict__ Woe,
                                               unsigned short* __restrict__ Wefrag,
                                               unsigned short* __restrict__ Woefrag,
                                               float* __restrict__ wa_sum)
{
    const int tid = threadIdx.x;
    if (tid < 32) {
        float4 w = *reinterpret_cast<const float4*>(&Wa[tid * 4]);
        wa_sum[tid] = w.x + w.y + w.z + w.w;
    }
    for (int idx = tid; idx < 8192; idx += 256) {
        int j = idx & 7, l = (idx >> 3) & 63, th = idx >> 9;
        int h = th & 1, t = th >> 1;
        int k = 32 * h + (l >> 4) * 8 + j;
        int c = 16 * t + (l & 15);
        Wefrag[idx] = f2bf(We[(64 + k) * 128 + c]);
    }
    for (int idx = tid; idx < 4096; idx += 256) {
        int j = idx & 7, l = (idx >> 3) & 63, uk = idx >> 9;
        int ks = uk & 3, u = uk >> 2;
        int k = 32 * ks + (l >> 4) * 8 + j;
        int c = 16 * u + (l & 15);
        Woefrag[idx] = f2bf(Woe[k * 32 + c]);
    }
}

// ---------------------------------------------------------------------------
// k_proj: out[mode] = nfeats @ W + (bias if mode 0)  (f32 vector GEMM)
// ---------------------------------------------------------------------------
__global__ __launch_bounds__(256) void k_proj(
    const float* __restrict__ nf, const float* __restrict__ Wn,
    const float* __restrict__ bn, const float* __restrict__ We,
    float* __restrict__ nproj, float* __restrict__ Psrc, float* __restrict__ Pdst)
{
    __shared__ __align__(16) float sA[64 * 68];
    __shared__ __align__(16) float sW[64 * 128];
    const int tid = threadIdx.x;
    const int mode = blockIdx.y;
    const int nBase = blockIdx.x * 64;

    const float* W = (mode == 0) ? Wn : (mode == 1 ? We : We + 128 * 128);
    float* outp = (mode == 0) ? nproj : (mode == 1 ? Psrc : Pdst);

    #pragma unroll
    for (int q = 0; q < 4; ++q) {
        int idx = q * 256 + tid;
        int e = idx >> 4, c4 = idx & 15;
        int row = nBase + e;
        float4 v = make_float4(0.f, 0.f, 0.f, 0.f);
        if (row < NN) v = *reinterpret_cast<const float4*>(&nf[row * 64 + c4 * 4]);
        *reinterpret_cast<float4*>(&sA[e * 68 + c4 * 4]) = v;
    }
    #pragma unroll
    for (int q = 0; q < 8; ++q) {
        int idx = q * 256 + tid;
        *reinterpret_cast<float4*>(&sW[idx * 4]) =
            *reinterpret_cast<const float4*>(&W[idx * 4]);
    }
    __syncthreads();

    const int jt = tid & 15, et = tid >> 4;
    float acc[4][8];
    #pragma unroll
    for (int i = 0; i < 4; ++i)
        #pragma unroll
        for (int j = 0; j < 8; ++j) acc[i][j] = 0.f;

    #pragma unroll 2
    for (int kk4 = 0; kk4 < 16; ++kk4) {
        float4 a4[4];
        #pragma unroll
        for (int i = 0; i < 4; ++i)
            a4[i] = *reinterpret_cast<const float4*>(&sA[(4 * et + i) * 68 + 4 * kk4]);
        #pragma unroll
        for (int c = 0; c < 4; ++c) {
            int kk = 4 * kk4 + c;
            float4 b0 = *reinterpret_cast<const float4*>(&sW[kk * 128 + 4 * jt]);
            float4 b1 = *reinterpret_cast<const float4*>(&sW[kk * 128 + 64 + 4 * jt]);
            #pragma unroll
            for (int i = 0; i < 4; ++i) {
                float av = (&a4[i].x)[c];
                acc[i][0] = fmaf(av, b0.x, acc[i][0]);
                acc[i][1] = fmaf(av, b0.y, acc[i][1]);
                acc[i][2] = fmaf(av, b0.z, acc[i][2]);
                acc[i][3] = fmaf(av, b0.w, acc[i][3]);
                acc[i][4] = fmaf(av, b1.x, acc[i][4]);
                acc[i][5] = fmaf(av, b1.y, acc[i][5]);
                acc[i][6] = fmaf(av, b1.z, acc[i][6]);
                acc[i][7] = fmaf(av, b1.w, acc[i][7]);
            }
        }
    }

    float4 bias0 = make_float4(0.f, 0.f, 0.f, 0.f), bias1 = bias0;
    if (mode == 0) {
        bias0 = *reinterpret_cast<const float4*>(&bn[4 * jt]);
        bias1 = *reinterpret_cast<const float4*>(&bn[64 + 4 * jt]);
    }
    #pragma unroll
    for (int i = 0; i < 4; ++i) {
        int row = nBase + 4 * et + i;
        if (row >= NN) continue;
        float4 r0 = make_float4(acc[i][0] + bias0.x, acc[i][1] + bias0.y,
                                acc[i][2] + bias0.z, acc[i][3] + bias0.w);
        float4 r1 = make_float4(acc[i][4] + bias1.x, acc[i][5] + bias1.y,
                                acc[i][6] + bias1.z, acc[i][7] + bias1.w);
        *reinterpret_cast<float4*>(&outp[row * 128 + 4 * jt]) = r0;
        *reinterpret_cast<float4*>(&outp[row * 128 + 64 + 4 * jt]) = r1;
    }
}

// ---------------------------------------------------------------------------
// k_edge (R9): 64 edges/block, 4 waves, wave w owns rows 16w..16w+15.
//   ph1: MFMA ef@We_mid -> acc[8] (col-sliced per lane)
//   ph2: raw acc -> fbuf bf16 [64][136]   (B1)
//   ph3: thread=(e,q): coalesced float4 Psrc/Pdst gather, f=lrelu(raw+ps+pd)
//        in-place fbuf rewrite, a-dot + 4-lane shfl reduce, CSR fill  (B2)
//   ph4: e_out MFMA: A-frags b128 from fbuf, B from Woefrag, +boe, store.
// ---------------------------------------------------------------------------
__global__ __launch_bounds__(256) void k_edge(
    const float* __restrict__ ef, const int* __restrict__ src,
    const int* __restrict__ dst,
    const unsigned short* __restrict__ Wefrag,
    const unsigned short* __restrict__ Woefrag,
    const float* __restrict__ wa_sum,
    const float* __restrict__ boe,
    const float* __restrict__ Psrc, const float* __restrict__ Pdst,
    int* __restrict__ cursor, int* __restrict__ srcs,
    float* __restrict__ exs, float* __restrict__ e_out)
{
    __shared__ __align__(16) unsigned short fbuf[64 * 136];  // 17.4 KB
    __shared__ __align__(16) int sidx[128];     // src[0..63], dst[64..127]
    __shared__ __align__(16) float swa[32];

    const int tid = threadIdx.x;
    const int w = tid >> 6, l = tid & 63;
    const int g = l >> 4, c16 = l & 15;
    const int eBase = blockIdx.x * 64;
    const int rowBase = eBase + 16 * w;

    if (tid < 64) { sidx[tid] = src[eBase + tid]; sidx[64 + tid] = dst[eBase + tid]; }
    else if (tid < 96) swa[tid - 64] = wa_sum[tid - 64];

    // ---- ph1: A-frags from ef (row = c16, k = 32h + 8g + j), MFMA ----
    bf16x8 afrag[2];
    #pragma unroll
    for (int h = 0; h < 2; ++h) {
        const float* ap = &ef[(size_t)(rowBase + c16) * 64 + 32 * h + 8 * g];
        float4 a0 = *reinterpret_cast<const float4*>(ap);
        float4 a1 = *reinterpret_cast<const float4*>(ap + 4);
        bf16x8 v;
        v[0] = (__bf16)a0.x; v[1] = (__bf16)a0.y;
        v[2] = (__bf16)a0.z; v[3] = (__bf16)a0.w;
        v[4] = (__bf16)a1.x; v[5] = (__bf16)a1.y;
        v[6] = (__bf16)a1.z; v[7] = (__bf16)a1.w;
        afrag[h] = v;
    }

    f32x4 acc[8];
    #pragma unroll
    for (int t = 0; t < 8; ++t) {
        f32x4 z = {0.f, 0.f, 0.f, 0.f};
        acc[t] = z;
        #pragma unroll
        for (int h = 0; h < 2; ++h) {
            bf16x8 b = *reinterpret_cast<const bf16x8*>(
                &Wefrag[((size_t)(t * 2 + h) * 64 + l) * 8]);
            acc[t] = __builtin_amdgcn_mfma_f32_16x16x32_bf16(afrag[h], b, acc[t], 0, 0, 0);
        }
    }

    // ---- ph2: raw acc -> fbuf (bf16). C layout: row=4g+reg, col=16t+c16 ----
    #pragma unroll
    for (int t = 0; t < 8; ++t)
        #pragma unroll
        for (int r = 0; r < 4; ++r)
            fbuf[(16 * w + 4 * g + r) * 136 + 16 * t + c16] = f2bf(acc[t][r]);

    __syncthreads();   // B1

    // ---- ph3: thread=(e,q) owns cols {16j+4q..+3, j=0..7} of edge e ----
    {
        const int e = tid >> 2, q = tid & 3;
        const int s = sidx[e], d = sidx[64 + e];
        float4 wlo = *reinterpret_cast<const float4*>(&swa[4 * q]);
        float4 whi = *reinterpret_cast<const float4*>(&swa[16 + 4 * q]);
        float ah[4] = {0.f, 0.f, 0.f, 0.f};
        #pragma unroll
        for (int j = 0; j < 8; ++j) {
            int col = 16 * j + 4 * q;
            float4 ps = *reinterpret_cast<const float4*>(&Psrc[(size_t)s * 128 + col]);
            float4 pd = *reinterpret_cast<const float4*>(&Pdst[(size_t)d * 128 + col]);
            ushort4 rw = *reinterpret_cast<const ushort4*>(&fbuf[e * 136 + col]);
            float f0 = lrelu(bf2f(rw.x) + ps.x + pd.x);
            float f1 = lrelu(bf2f(rw.y) + ps.y + pd.y);
            float f2 = lrelu(bf2f(rw.z) + ps.z + pd.z);
            float f3 = lrelu(bf2f(rw.w) + ps.w + pd.w);
            const float4& wv = (j & 1) ? whi : wlo;
            int h = j >> 1;
            ah[h] = fmaf(f0, wv.x, ah[h]);
            ah[h] = fmaf(f1, wv.y, ah[h]);
            ah[h] = fmaf(f2, wv.z, ah[h]);
            ah[h] = fmaf(f3, wv.w, ah[h]);
            ushort4 fw;
            fw.x = f2bf(f0); fw.y = f2bf(f1); fw.z = f2bf(f2); fw.w = f2bf(f3);
            *reinterpret_cast<ushort4*>(&fbuf[e * 136 + col]) = fw;
        }
        // reduce heads across the 4 lanes of this edge
        #pragma unroll
        for (int h = 0; h < 4; ++h) {
            float v = ah[h];
            v += __shfl_xor(v, 1);
            v += __shfl_xor(v, 2);
            ah[h] = v;
        }
        // CSR fill
        int pos = 0;
        if (q == 0) pos = atomicAdd(&cursor[d], 1);
        pos = __shfl(pos, l & ~3);
        if (q == 0) srcs[pos] = s;
        float myA = (q == 0) ? ah[0] : (q == 1) ? ah[1] : (q == 2) ? ah[2] : ah[3];
        exs[(size_t)pos * 4 + q] = expf(myA);
    }

    __syncthreads();   // B2: f (bf16) ready for all rows

    // ---- ph4: e_out = f @ Woe + boe via MFMA ----
    {
        bf16x8 af[4];
        #pragma unroll
        for (int ks = 0; ks < 4; ++ks)
            af[ks] = *reinterpret_cast<const bf16x8*>(
                &fbuf[(16 * w + c16) * 136 + 32 * ks + 8 * g]);
        #pragma unroll
        for (int u = 0; u < 2; ++u) {
            f32x4 o = {0.f, 0.f, 0.f, 0.f};
            #pragma unroll
            for (int ks = 0; ks < 4; ++ks) {
                bf16x8 b = *reinterpret_cast<const bf16x8*>(
                    &Woefrag[((size_t)(u * 4 + ks) * 64 + l) * 8]);
                o = __builtin_amdgcn_mfma_f32_16x16x32_bf16(af[ks], b, o, 0, 0, 0);
            }
            float bo = boe[16 * u + c16];
            #pragma unroll
            for (int r = 0; r < 4; ++r)
                e_out[(size_t)(eBase + 16 * w + 4 * g + r) * 32 + 16 * u + c16] =
                    o[r] + bo;
        }
    }
}

// ---------------------------------------------------------------------------
// k_agg: per node n (2 nodes/block, 128 threads each, thread owns output j)
// ---------------------------------------------------------------------------
__global__ __launch_bounds__(256) void k_agg(
    const int* __restrict__ rowptr, const int* __restrict__ srcs,
    const float* __restrict__ exs, const float* __restrict__ nproj,
    float* __restrict__ hbuf)
{
    const int tid = threadIdx.x;
    const int j = tid & 127;
    const int n = blockIdx.x * 2 + (tid >> 7);
    if (n >= NN) return;
    const int beg = rowptr[n], end = rowptr[n + 1];
    const int h = j >> 5;
    float val = 0.f, den = 0.f;
    int s_next = (beg < end) ? srcs[beg] : 0;
    for (int p = beg; p < end; ++p) {
        int s = s_next;
        if (p + 1 < end) s_next = srcs[p + 1];
        float ex = exs[(size_t)p * 4 + h];
        val = fmaf(ex, nproj[(size_t)s * 128 + j], val);
        den += ex;
    }
    float out = (end > beg) ? (val / den) : nproj[(size_t)n * 128 + j];
    hbuf[(size_t)n * 128 + j] = out;
}

// ---------------------------------------------------------------------------
// k_node_out: h_out = hbuf @ Won + bon
// ---------------------------------------------------------------------------
__global__ __launch_bounds__(256) void k_node_out(
    const float* __restrict__ hbuf, const float* __restrict__ Won,
    const float* __restrict__ bon, float* __restrict__ h_out)
{
    __shared__ __align__(16) float sh[64 * 132];
    __shared__ __align__(16) float sWon[128 * 32];
    __shared__ __align__(16) float sbon[32];
    const int tid = threadIdx.x;
    const int nBase = blockIdx.x * 64;

    #pragma unroll
    for (int q = 0; q < 8; ++q) {
        int idx = q * 256 + tid;
        int n = idx >> 5, c4 = idx & 31;
        int row = nBase + n;
        float4 v = make_float4(0.f, 0.f, 0.f, 0.f);
        if (row < NN)
            v = *reinterpret_cast<const float4*>(&hbuf[(size_t)row * 128 + c4 * 4]);
        *reinterpret_cast<float4*>(&sh[n * 132 + c4 * 4]) = v;
    }
    #pragma unroll
    for (int q = 0; q < 4; ++q) {
        int idx = q * 256 + tid;
        *reinterpret_cast<float4*>(&sWon[idx * 4]) =
            *reinterpret_cast<const float4*>(&Won[idx * 4]);
    }
    if (tid < 32) sbon[tid] = bon[tid];
    __syncthreads();

    int n = tid >> 2, q = tid & 3;
    int j0 = q * 8;
    int row = nBase + n;
    float4 r0 = make_float4(0.f, 0.f, 0.f, 0.f), r1 = r0;
    #pragma unroll 4
    for (int k = 0; k < 128; k += 4) {
        float4 fv = *reinterpret_cast<const float4*>(&sh[n * 132 + k]);
        #pragma unroll
        for (int c = 0; c < 4; ++c) {
            float fk = (&fv.x)[c];
            float4 w0 = *reinterpret_cast<const float4*>(&sWon[(k + c) * 32 + j0]);
            float4 w1 = *reinterpret_cast<const float4*>(&sWon[(k + c) * 32 + j0 + 4]);
            r0.x = fmaf(fk, w0.x, r0.x); r0.y = fmaf(fk, w0.y, r0.y);
            r0.z = fmaf(fk, w0.z, r0.z); r0.w = fmaf(fk, w0.w, r0.w);
            r1.x = fmaf(fk, w1.x, r1.x); r1.y = fmaf(fk, w1.y, r1.y);
            r1.z = fmaf(fk, w1.z, r1.z); r1.w = fmaf(fk, w1.w, r1.w);
        }
    }
    if (row < NN) {
        float4 b0 = *reinterpret_cast<const float4*>(&sbon[j0]);
        float4 b1 = *reinterpret_cast<const float4*>(&sbon[j0 + 4]);
        r0.x += b0.x; r0.y += b0.y; r0.z += b0.z; r0.w += b0.w;
        r1.x += b1.x; r1.y += b1.y; r1.z += b1.z; r1.w += b1.w;
        size_t o = (size_t)row * 32 + j0;
        *reinterpret_cast<float4*>(&h_out[o]) = r0;
        *reinterpret_cast<float4*>(&h_out[o + 4]) = r1;
    }
}

extern "C" void kernel_launch(void* const* d_in, const int* in_sizes, int n_in,
                              void* d_out, int out_size, void* d_ws, size_t ws_size,
                              hipStream_t stream) {
    const float* nfeats = (const float*)d_in[0];
    const float* efeats = (const float*)d_in[1];
    const int*   src    = (const int*)d_in[2];
    const int*   dst    = (const int*)d_in[3];
    const float* Wn     = (const float*)d_in[4];
    const float* bn     = (const float*)d_in[5];
    const float* We     = (const float*)d_in[6];
    const float* Wa     = (const float*)d_in[7];
    const float* Won    = (const float*)d_in[8];
    const float* bon    = (const float*)d_in[9];
    const float* Woe    = (const float*)d_in[10];
    const float* boe    = (const float*)d_in[11];

    float* h_out = (float*)d_out;                 // [N,32]
    float* e_out = h_out + (size_t)NN * 32;       // [E,32]

    // ws layout: nproj[N*128]f | Psrc[N*128]f (hbuf aliases after k_edge) |
    //   Pdst[N*128]f | exs[E*4]f | deg[N]i | rowptr[N+1]i | cursor[N]i |
    //   srcs[E]i | bsum[256]i | wa_sum[32]f | Wefrag[8192]u16 | Woefrag[4096]u16
    float* nproj  = (float*)d_ws;
    float* Psrc   = nproj + (size_t)NN * 128;
    float* Pdst   = Psrc + (size_t)NN * 128;
    float* exs    = Pdst + (size_t)NN * 128;
    int*   deg    = (int*)(exs + (size_t)NE * 4);
    int*   rowptr = deg + NN;
    int*   cursor = rowptr + NN + 1;
    int*   srcs   = cursor + NN;
    int*   bsum   = srcs + NE;
    float* wa_sum = (float*)(bsum + 256);
    unsigned short* Wefrag =
        (unsigned short*)(((uintptr_t)(wa_sum + 32) + 15) & ~(uintptr_t)15);
    unsigned short* Woefrag = Wefrag + 8192;
    float* hbuf   = Psrc;                         // Psrc dead after k_edge

    hipMemsetAsync(deg, 0, NN * sizeof(int), stream);

    k_count<<<1024, 256, 0, stream>>>(dst, deg);
    k_scan_blk<<<NB, 256, 0, stream>>>(deg, rowptr, bsum);
    k_scan_top<<<1, 256, 0, stream>>>(bsum, rowptr);
    k_scan_add<<<NB, 256, 0, stream>>>(rowptr, bsum, cursor);

    k_prepw<<<1, 256, 0, stream>>>(We, Wa, Woe, Wefrag, Woefrag, wa_sum);

    dim3 gProj((NN + 63) / 64, 3);
    k_proj<<<gProj, 256, 0, stream>>>(nfeats, Wn, bn, We, nproj, Psrc, Pdst);

    k_edge<<<NE / 64, 256, 0, stream>>>(efeats, src, dst, Wefrag, Woefrag,
                                        wa_sum, boe, Psrc, Pdst,
                                        cursor, srcs, exs, e_out);

    k_agg<<<(NN + 1) / 2, 256, 0, stream>>>(rowptr, srcs, exs, nproj, hbuf);

    k_node_out<<<(NN + 63) / 64, 256, 0, stream>>>(hbuf, Won, bon, h_out);
}

// Round 10
// 649.141 us; speedup vs baseline: 2.6798x; 1.0913x over previous
//
#include <hip/hip_runtime.h>
#include <hip/hip_bf16.h>

// EGATConv fused forward, MI355X.
// R3: dst-CSR replaced 102.4M f32 atomics (k_edge 1451->343us).
// R5/R6: main edge GEMM -> bf16 MFMA.
// R9: coalesced epilogue gather + e_out MFMA; LDS 50.7->18KB, Occ 21->55%,
//     k_edge 352->253us (verified). "Others" now dominate (~455us).
// R10: (a) k_agg edge-loop unrolled 4x (independent loads in flight -> /4
//      latency chain; k_agg was 1-deep pipelined on random nproj rows);
//      (b) Psrc/Pdst stored bf16 (tables 25.6->12.8MB each: L2 residency,
//      k_edge FETCH drop, k_proj writes halved for modes 1/2).
// Algebra: stack@We = Psrc[src] + ef@We_mid + Pdst[dst]; a = f . rowsum(Wa);
// softmax max-shift skipped (|a|~0.3); normalization folded to node level.

#define NN 50000
#define NE 800000
#define NB ((NN + 255) / 256)   // 196 scan blocks

typedef __attribute__((ext_vector_type(8))) __bf16 bf16x8;
typedef __attribute__((ext_vector_type(4))) float f32x4;

__device__ __forceinline__ float lrelu(float x) { return x > 0.f ? x : 0.01f * x; }
__device__ __forceinline__ unsigned short f2bf(float x) {
    __bf16 b = (__bf16)x; return *reinterpret_cast<unsigned short*>(&b);
}
__device__ __forceinline__ float bf2f(unsigned short u) {
    __bf16 b = *reinterpret_cast<__bf16*>(&u); return (float)b;
}

// ---------------------------------------------------------------------------
// k_count: deg[n] = #edges with dst==n
// ---------------------------------------------------------------------------
__global__ __launch_bounds__(256) void k_count(const int* __restrict__ dst,
                                               int* __restrict__ deg)
{
    int i = blockIdx.x * blockDim.x + threadIdx.x;
    int stride = gridDim.x * blockDim.x;
    for (; i < NE; i += stride) atomicAdd(&deg[dst[i]], 1);
}

// ---------------------------------------------------------------------------
// 3-kernel exclusive scan of deg[NN] -> rowptr/cursor
// ---------------------------------------------------------------------------
__global__ __launch_bounds__(256) void k_scan_blk(const int* __restrict__ deg,
                                                  int* __restrict__ rowptr,
                                                  int* __restrict__ bsum)
{
    __shared__ int wsum[4];
    const int tid = threadIdx.x, lane = tid & 63, wid = tid >> 6;
    const int i = blockIdx.x * 256 + tid;
    int v = (i < NN) ? deg[i] : 0;
    int x = v;
    #pragma unroll
    for (int off = 1; off < 64; off <<= 1) {
        int t = __shfl_up(x, off);
        if (lane >= off) x += t;
    }
    if (lane == 63) wsum[wid] = x;
    __syncthreads();
    if (tid == 0) {
        int s = 0;
        #pragma unroll
        for (int w = 0; w < 4; ++w) { int t = wsum[w]; wsum[w] = s; s += t; }
        bsum[blockIdx.x] = s;
    }
    __syncthreads();
    if (i < NN) rowptr[i] = wsum[wid] + x - v;   // block-local exclusive
}

__global__ __launch_bounds__(256) void k_scan_top(int* __restrict__ bsum,
                                                  int* __restrict__ rowptr)
{
    __shared__ int wsum[4];
    const int tid = threadIdx.x, lane = tid & 63, wid = tid >> 6;
    int v = (tid < NB) ? bsum[tid] : 0;
    int x = v;
    #pragma unroll
    for (int off = 1; off < 64; off <<= 1) {
        int t = __shfl_up(x, off);
        if (lane >= off) x += t;
    }
    if (lane == 63) wsum[wid] = x;
    __syncthreads();
    if (tid == 0) {
        int s = 0;
        #pragma unroll
        for (int w = 0; w < 4; ++w) { int t = wsum[w]; wsum[w] = s; s += t; }
    }
    __syncthreads();
    int excl = wsum[wid] + x - v;
    if (tid < NB) bsum[tid] = excl;
    if (tid == NB - 1) rowptr[NN] = excl + v;    // total == NE
}

__global__ __launch_bounds__(256) void k_scan_add(int* __restrict__ rowptr,
                                                  const int* __restrict__ bsum,
                                                  int* __restrict__ cursor)
{
    const int i = blockIdx.x * 256 + threadIdx.x;
    if (i < NN) {
        int r = rowptr[i] + bsum[blockIdx.x];
        rowptr[i] = r;
        cursor[i] = r;
    }
}

// ---------------------------------------------------------------------------
// k_prepw: bf16 B-fragment tables (We_mid -> Wefrag, Woe -> Woefrag) + wa_sum.
// ---------------------------------------------------------------------------
__global__ __launch_bounds__(256) void k_prepw(const float* __restrict__ We,
                                               const float* __restrict__ Wa,
                                               const float* __restrict__ Woe,
                                               unsigned short* __restrict__ Wefrag,
                                               unsigned short* __restrict__ Woefrag,
                                               float* __restrict__ wa_sum)
{
    const int tid = threadIdx.x;
    if (tid < 32) {
        float4 w = *reinterpret_cast<const float4*>(&Wa[tid * 4]);
        wa_sum[tid] = w.x + w.y + w.z + w.w;
    }
    for (int idx = tid; idx < 8192; idx += 256) {
        int j = idx & 7, l = (idx >> 3) & 63, th = idx >> 9;
        int h = th & 1, t = th >> 1;
        int k = 32 * h + (l >> 4) * 8 + j;
        int c = 16 * t + (l & 15);
        Wefrag[idx] = f2bf(We[(64 + k) * 128 + c]);
    }
    for (int idx = tid; idx < 4096; idx += 256) {
        int j = idx & 7, l = (idx >> 3) & 63, uk = idx >> 9;
        int ks = uk & 3, u = uk >> 2;
        int k = 32 * ks + (l >> 4) * 8 + j;
        int c = 16 * u + (l & 15);
        Woefrag[idx] = f2bf(Woe[k * 32 + c]);
    }
}

// ---------------------------------------------------------------------------
// k_proj: mode 0: nproj = nf@Wn + bn (f32); mode 1/2: Psb/Pdb = bf16(nf@We_*)
// ---------------------------------------------------------------------------
__global__ __launch_bounds__(256) void k_proj(
    const float* __restrict__ nf, const float* __restrict__ Wn,
    const float* __restrict__ bn, const float* __restrict__ We,
    float* __restrict__ nproj, unsigned short* __restrict__ Psb,
    unsigned short* __restrict__ Pdb)
{
    __shared__ __align__(16) float sA[64 * 68];
    __shared__ __align__(16) float sW[64 * 128];
    const int tid = threadIdx.x;
    const int mode = blockIdx.y;
    const int nBase = blockIdx.x * 64;

    const float* W = (mode == 0) ? Wn : (mode == 1 ? We : We + 128 * 128);

    #pragma unroll
    for (int q = 0; q < 4; ++q) {
        int idx = q * 256 + tid;
        int e = idx >> 4, c4 = idx & 15;
        int row = nBase + e;
        float4 v = make_float4(0.f, 0.f, 0.f, 0.f);
        if (row < NN) v = *reinterpret_cast<const float4*>(&nf[row * 64 + c4 * 4]);
        *reinterpret_cast<float4*>(&sA[e * 68 + c4 * 4]) = v;
    }
    #pragma unroll
    for (int q = 0; q < 8; ++q) {
        int idx = q * 256 + tid;
        *reinterpret_cast<float4*>(&sW[idx * 4]) =
            *reinterpret_cast<const float4*>(&W[idx * 4]);
    }
    __syncthreads();

    const int jt = tid & 15, et = tid >> 4;
    float acc[4][8];
    #pragma unroll
    for (int i = 0; i < 4; ++i)
        #pragma unroll
        for (int j = 0; j < 8; ++j) acc[i][j] = 0.f;

    #pragma unroll 2
    for (int kk4 = 0; kk4 < 16; ++kk4) {
        float4 a4[4];
        #pragma unroll
        for (int i = 0; i < 4; ++i)
            a4[i] = *reinterpret_cast<const float4*>(&sA[(4 * et + i) * 68 + 4 * kk4]);
        #pragma unroll
        for (int c = 0; c < 4; ++c) {
            int kk = 4 * kk4 + c;
            float4 b0 = *reinterpret_cast<const float4*>(&sW[kk * 128 + 4 * jt]);
            float4 b1 = *reinterpret_cast<const float4*>(&sW[kk * 128 + 64 + 4 * jt]);
            #pragma unroll
            for (int i = 0; i < 4; ++i) {
                float av = (&a4[i].x)[c];
                acc[i][0] = fmaf(av, b0.x, acc[i][0]);
                acc[i][1] = fmaf(av, b0.y, acc[i][1]);
                acc[i][2] = fmaf(av, b0.z, acc[i][2]);
                acc[i][3] = fmaf(av, b0.w, acc[i][3]);
                acc[i][4] = fmaf(av, b1.x, acc[i][4]);
                acc[i][5] = fmaf(av, b1.y, acc[i][5]);
                acc[i][6] = fmaf(av, b1.z, acc[i][6]);
                acc[i][7] = fmaf(av, b1.w, acc[i][7]);
            }
        }
    }

    if (mode == 0) {
        float4 bias0 = *reinterpret_cast<const float4*>(&bn[4 * jt]);
        float4 bias1 = *reinterpret_cast<const float4*>(&bn[64 + 4 * jt]);
        #pragma unroll
        for (int i = 0; i < 4; ++i) {
            int row = nBase + 4 * et + i;
            if (row >= NN) continue;
            float4 r0 = make_float4(acc[i][0] + bias0.x, acc[i][1] + bias0.y,
                                    acc[i][2] + bias0.z, acc[i][3] + bias0.w);
            float4 r1 = make_float4(acc[i][4] + bias1.x, acc[i][5] + bias1.y,
                                    acc[i][6] + bias1.z, acc[i][7] + bias1.w);
            *reinterpret_cast<float4*>(&nproj[(size_t)row * 128 + 4 * jt]) = r0;
            *reinterpret_cast<float4*>(&nproj[(size_t)row * 128 + 64 + 4 * jt]) = r1;
        }
    } else {
        unsigned short* outp = (mode == 1) ? Psb : Pdb;
        #pragma unroll
        for (int i = 0; i < 4; ++i) {
            int row = nBase + 4 * et + i;
            if (row >= NN) continue;
            ushort4 u0, u1;
            u0.x = f2bf(acc[i][0]); u0.y = f2bf(acc[i][1]);
            u0.z = f2bf(acc[i][2]); u0.w = f2bf(acc[i][3]);
            u1.x = f2bf(acc[i][4]); u1.y = f2bf(acc[i][5]);
            u1.z = f2bf(acc[i][6]); u1.w = f2bf(acc[i][7]);
            *reinterpret_cast<ushort4*>(&outp[(size_t)row * 128 + 4 * jt]) = u0;
            *reinterpret_cast<ushort4*>(&outp[(size_t)row * 128 + 64 + 4 * jt]) = u1;
        }
    }
}

// ---------------------------------------------------------------------------
// k_edge: 64 edges/block, 4 waves, wave w owns rows 16w..16w+15.
//   ph1: MFMA ef@We_mid -> acc[8]
//   ph2: raw acc -> fbuf bf16 [64][136]   (B1)
//   ph3: thread=(e,q): coalesced ushort4 Psb/Pdb gather (bf16, R10),
//        f=lrelu(raw+ps+pd), in-place fbuf rewrite, a-dot + shfl, CSR fill (B2)
//   ph4: e_out MFMA from fbuf + Woefrag, +boe, store.
// ---------------------------------------------------------------------------
__global__ __launch_bounds__(256) void k_edge(
    const float* __restrict__ ef, const int* __restrict__ src,
    const int* __restrict__ dst,
    const unsigned short* __restrict__ Wefrag,
    const unsigned short* __restrict__ Woefrag,
    const float* __restrict__ wa_sum,
    const float* __restrict__ boe,
    const unsigned short* __restrict__ Psb, const unsigned short* __restrict__ Pdb,
    int* __restrict__ cursor, int* __restrict__ srcs,
    float* __restrict__ exs, float* __restrict__ e_out)
{
    __shared__ __align__(16) unsigned short fbuf[64 * 136];  // 17.4 KB
    __shared__ __align__(16) int sidx[128];     // src[0..63], dst[64..127]
    __shared__ __align__(16) float swa[32];

    const int tid = threadIdx.x;
    const int w = tid >> 6, l = tid & 63;
    const int g = l >> 4, c16 = l & 15;
    const int eBase = blockIdx.x * 64;
    const int rowBase = eBase + 16 * w;

    if (tid < 64) { sidx[tid] = src[eBase + tid]; sidx[64 + tid] = dst[eBase + tid]; }
    else if (tid < 96) swa[tid - 64] = wa_sum[tid - 64];

    // ---- ph1: A-frags from ef (row = c16, k = 32h + 8g + j), MFMA ----
    bf16x8 afrag[2];
    #pragma unroll
    for (int h = 0; h < 2; ++h) {
        const float* ap = &ef[(size_t)(rowBase + c16) * 64 + 32 * h + 8 * g];
        float4 a0 = *reinterpret_cast<const float4*>(ap);
        float4 a1 = *reinterpret_cast<const float4*>(ap + 4);
        bf16x8 v;
        v[0] = (__bf16)a0.x; v[1] = (__bf16)a0.y;
        v[2] = (__bf16)a0.z; v[3] = (__bf16)a0.w;
        v[4] = (__bf16)a1.x; v[5] = (__bf16)a1.y;
        v[6] = (__bf16)a1.z; v[7] = (__bf16)a1.w;
        afrag[h] = v;
    }

    f32x4 acc[8];
    #pragma unroll
    for (int t = 0; t < 8; ++t) {
        f32x4 z = {0.f, 0.f, 0.f, 0.f};
        acc[t] = z;
        #pragma unroll
        for (int h = 0; h < 2; ++h) {
            bf16x8 b = *reinterpret_cast<const bf16x8*>(
                &Wefrag[((size_t)(t * 2 + h) * 64 + l) * 8]);
            acc[t] = __builtin_amdgcn_mfma_f32_16x16x32_bf16(afrag[h], b, acc[t], 0, 0, 0);
        }
    }

    // ---- ph2: raw acc -> fbuf (bf16). C layout: row=4g+reg, col=16t+c16 ----
    #pragma unroll
    for (int t = 0; t < 8; ++t)
        #pragma unroll
        for (int r = 0; r < 4; ++r)
            fbuf[(16 * w + 4 * g + r) * 136 + 16 * t + c16] = f2bf(acc[t][r]);

    __syncthreads();   // B1

    // ---- ph3: thread=(e,q) owns cols {16j+4q..+3, j=0..7} of edge e ----
    {
        const int e = tid >> 2, q = tid & 3;
        const int s = sidx[e], d = sidx[64 + e];
        float4 wlo = *reinterpret_cast<const float4*>(&swa[4 * q]);
        float4 whi = *reinterpret_cast<const float4*>(&swa[16 + 4 * q]);
        float ah[4] = {0.f, 0.f, 0.f, 0.f};
        #pragma unroll
        for (int j = 0; j < 8; ++j) {
            int col = 16 * j + 4 * q;
            ushort4 psu = *reinterpret_cast<const ushort4*>(&Psb[(size_t)s * 128 + col]);
            ushort4 pdu = *reinterpret_cast<const ushort4*>(&Pdb[(size_t)d * 128 + col]);
            ushort4 rw = *reinterpret_cast<const ushort4*>(&fbuf[e * 136 + col]);
            float f0 = lrelu(bf2f(rw.x) + bf2f(psu.x) + bf2f(pdu.x));
            float f1 = lrelu(bf2f(rw.y) + bf2f(psu.y) + bf2f(pdu.y));
            float f2 = lrelu(bf2f(rw.z) + bf2f(psu.z) + bf2f(pdu.z));
            float f3 = lrelu(bf2f(rw.w) + bf2f(psu.w) + bf2f(pdu.w));
            const float4& wv = (j & 1) ? whi : wlo;
            int h = j >> 1;
            ah[h] = fmaf(f0, wv.x, ah[h]);
            ah[h] = fmaf(f1, wv.y, ah[h]);
            ah[h] = fmaf(f2, wv.z, ah[h]);
            ah[h] = fmaf(f3, wv.w, ah[h]);
            ushort4 fw;
            fw.x = f2bf(f0); fw.y = f2bf(f1); fw.z = f2bf(f2); fw.w = f2bf(f3);
            *reinterpret_cast<ushort4*>(&fbuf[e * 136 + col]) = fw;
        }
        // reduce heads across the 4 lanes of this edge
        #pragma unroll
        for (int h = 0; h < 4; ++h) {
            float v = ah[h];
            v += __shfl_xor(v, 1);
            v += __shfl_xor(v, 2);
            ah[h] = v;
        }
        // CSR fill
        int pos = 0;
        if (q == 0) pos = atomicAdd(&cursor[d], 1);
        pos = __shfl(pos, l & ~3);
        if (q == 0) srcs[pos] = s;
        float myA = (q == 0) ? ah[0] : (q == 1) ? ah[1] : (q == 2) ? ah[2] : ah[3];
        exs[(size_t)pos * 4 + q] = expf(myA);
    }

    __syncthreads();   // B2: f (bf16) ready for all rows

    // ---- ph4: e_out = f @ Woe + boe via MFMA ----
    {
        bf16x8 af[4];
        #pragma unroll
        for (int ks = 0; ks < 4; ++ks)
            af[ks] = *reinterpret_cast<const bf16x8*>(
                &fbuf[(16 * w + c16) * 136 + 32 * ks + 8 * g]);
        #pragma unroll
        for (int u = 0; u < 2; ++u) {
            f32x4 o = {0.f, 0.f, 0.f, 0.f};
            #pragma unroll
            for (int ks = 0; ks < 4; ++ks) {
                bf16x8 b = *reinterpret_cast<const bf16x8*>(
                    &Woefrag[((size_t)(u * 4 + ks) * 64 + l) * 8]);
                o = __builtin_amdgcn_mfma_f32_16x16x32_bf16(af[ks], b, o, 0, 0, 0);
            }
            float bo = boe[16 * u + c16];
            #pragma unroll
            for (int r = 0; r < 4; ++r)
                e_out[(size_t)(eBase + 16 * w + 4 * g + r) * 32 + 16 * u + c16] =
                    o[r] + bo;
        }
    }
}

// ---------------------------------------------------------------------------
// k_agg (R10): 4x unrolled edge loop — 4 independent srcs/exs/nproj loads
// in flight per step (was 1-deep pipelined -> serial L3 latency chain).
// ---------------------------------------------------------------------------
__global__ __launch_bounds__(256) void k_agg(
    const int* __restrict__ rowptr, const int* __restrict__ srcs,
    const float* __restrict__ exs, const float* __restrict__ nproj,
    float* __restrict__ hbuf)
{
    const int tid = threadIdx.x;
    const int j = tid & 127;
    const int n = blockIdx.x * 2 + (tid >> 7);
    if (n >= NN) return;
    const int beg = rowptr[n], end = rowptr[n + 1];
    const int h = j >> 5;
    float val = 0.f, den = 0.f;
    int p = beg;
    for (; p + 4 <= end; p += 4) {
        int s0 = srcs[p],     s1 = srcs[p + 1];
        int s2 = srcs[p + 2], s3 = srcs[p + 3];
        float e0 = exs[(size_t)p * 4 + h];
        float e1 = exs[(size_t)(p + 1) * 4 + h];
        float e2 = exs[(size_t)(p + 2) * 4 + h];
        float e3 = exs[(size_t)(p + 3) * 4 + h];
        float n0 = nproj[(size_t)s0 * 128 + j];
        float n1 = nproj[(size_t)s1 * 128 + j];
        float n2 = nproj[(size_t)s2 * 128 + j];
        float n3 = nproj[(size_t)s3 * 128 + j];
        val = fmaf(e0, n0, val); val = fmaf(e1, n1, val);
        val = fmaf(e2, n2, val); val = fmaf(e3, n3, val);
        den += e0 + e1 + e2 + e3;
    }
    for (; p < end; ++p) {
        int s = srcs[p];
        float ex = exs[(size_t)p * 4 + h];
        val = fmaf(ex, nproj[(size_t)s * 128 + j], val);
        den += ex;
    }
    float out = (end > beg) ? (val / den) : nproj[(size_t)n * 128 + j];
    hbuf[(size_t)n * 128 + j] = out;
}

// ---------------------------------------------------------------------------
// k_node_out: h_out = hbuf @ Won + bon
// ---------------------------------------------------------------------------
__global__ __launch_bounds__(256) void k_node_out(
    const float* __restrict__ hbuf, const float* __restrict__ Won,
    const float* __restrict__ bon, float* __restrict__ h_out)
{
    __shared__ __align__(16) float sh[64 * 132];
    __shared__ __align__(16) float sWon[128 * 32];
    __shared__ __align__(16) float sbon[32];
    const int tid = threadIdx.x;
    const int nBase = blockIdx.x * 64;

    #pragma unroll
    for (int q = 0; q < 8; ++q) {
        int idx = q * 256 + tid;
        int n = idx >> 5, c4 = idx & 31;
        int row = nBase + n;
        float4 v = make_float4(0.f, 0.f, 0.f, 0.f);
        if (row < NN)
            v = *reinterpret_cast<const float4*>(&hbuf[(size_t)row * 128 + c4 * 4]);
        *reinterpret_cast<float4*>(&sh[n * 132 + c4 * 4]) = v;
    }
    #pragma unroll
    for (int q = 0; q < 4; ++q) {
        int idx = q * 256 + tid;
        *reinterpret_cast<float4*>(&sWon[idx * 4]) =
            *reinterpret_cast<const float4*>(&Won[idx * 4]);
    }
    if (tid < 32) sbon[tid] = bon[tid];
    __syncthreads();

    int n = tid >> 2, q = tid & 3;
    int j0 = q * 8;
    int row = nBase + n;
    float4 r0 = make_float4(0.f, 0.f, 0.f, 0.f), r1 = r0;
    #pragma unroll 4
    for (int k = 0; k < 128; k += 4) {
        float4 fv = *reinterpret_cast<const float4*>(&sh[n * 132 + k]);
        #pragma unroll
        for (int c = 0; c < 4; ++c) {
            float fk = (&fv.x)[c];
            float4 w0 = *reinterpret_cast<const float4*>(&sWon[(k + c) * 32 + j0]);
            float4 w1 = *reinterpret_cast<const float4*>(&sWon[(k + c) * 32 + j0 + 4]);
            r0.x = fmaf(fk, w0.x, r0.x); r0.y = fmaf(fk, w0.y, r0.y);
            r0.z = fmaf(fk, w0.z, r0.z); r0.w = fmaf(fk, w0.w, r0.w);
            r1.x = fmaf(fk, w1.x, r1.x); r1.y = fmaf(fk, w1.y, r1.y);
            r1.z = fmaf(fk, w1.z, r1.z); r1.w = fmaf(fk, w1.w, r1.w);
        }
    }
    if (row < NN) {
        float4 b0 = *reinterpret_cast<const float4*>(&sbon[j0]);
        float4 b1 = *reinterpret_cast<const float4*>(&sbon[j0 + 4]);
        r0.x += b0.x; r0.y += b0.y; r0.z += b0.z; r0.w += b0.w;
        r1.x += b1.x; r1.y += b1.y; r1.z += b1.z; r1.w += b1.w;
        size_t o = (size_t)row * 32 + j0;
        *reinterpret_cast<float4*>(&h_out[o]) = r0;
        *reinterpret_cast<float4*>(&h_out[o + 4]) = r1;
    }
}

extern "C" void kernel_launch(void* const* d_in, const int* in_sizes, int n_in,
                              void* d_out, int out_size, void* d_ws, size_t ws_size,
                              hipStream_t stream) {
    const float* nfeats = (const float*)d_in[0];
    const float* efeats = (const float*)d_in[1];
    const int*   src    = (const int*)d_in[2];
    const int*   dst    = (const int*)d_in[3];
    const float* Wn     = (const float*)d_in[4];
    const float* bn     = (const float*)d_in[5];
    const float* We     = (const float*)d_in[6];
    const float* Wa     = (const float*)d_in[7];
    const float* Won    = (const float*)d_in[8];
    const float* bon    = (const float*)d_in[9];
    const float* Woe    = (const float*)d_in[10];
    const float* boe    = (const float*)d_in[11];

    float* h_out = (float*)d_out;                 // [N,32]
    float* e_out = h_out + (size_t)NN * 32;       // [E,32]

    // ws layout: nproj f32[N*128] | Psb u16[N*128] | Pdb u16[N*128]
    //   (Psb+Pdb region re-aliased as hbuf f32[N*128] after k_edge) |
    //   exs f32[E*4] | deg[N]i | rowptr[N+1]i | cursor[N]i | srcs[E]i |
    //   bsum[256]i | wa_sum[32]f | Wefrag[8192]u16 | Woefrag[4096]u16
    float* nproj  = (float*)d_ws;
    unsigned short* Psb = (unsigned short*)(nproj + (size_t)NN * 128);
    unsigned short* Pdb = Psb + (size_t)NN * 128;
    float* exs    = (float*)(Pdb + (size_t)NN * 128);
    int*   deg    = (int*)(exs + (size_t)NE * 4);
    int*   rowptr = deg + NN;
    int*   cursor = rowptr + NN + 1;
    int*   srcs   = cursor + NN;
    int*   bsum   = srcs + NE;
    float* wa_sum = (float*)(bsum + 256);
    unsigned short* Wefrag =
        (unsigned short*)(((uintptr_t)(wa_sum + 32) + 15) & ~(uintptr_t)15);
    unsigned short* Woefrag = Wefrag + 8192;
    float* hbuf   = (float*)Psb;                  // P tables dead after k_edge

    hipMemsetAsync(deg, 0, NN * sizeof(int), stream);

    k_count<<<1024, 256, 0, stream>>>(dst, deg);
    k_scan_blk<<<NB, 256, 0, stream>>>(deg, rowptr, bsum);
    k_scan_top<<<1, 256, 0, stream>>>(bsum, rowptr);
    k_scan_add<<<NB, 256, 0, stream>>>(rowptr, bsum, cursor);

    k_prepw<<<1, 256, 0, stream>>>(We, Wa, Woe, Wefrag, Woefrag, wa_sum);

    dim3 gProj((NN + 63) / 64, 3);
    k_proj<<<gProj, 256, 0, stream>>>(nfeats, Wn, bn, We, nproj, Psb, Pdb);

    k_edge<<<NE / 64, 256, 0, stream>>>(efeats, src, dst, Wefrag, Woefrag,
                                        wa_sum, boe, Psb, Pdb,
                                        cursor, srcs, exs, e_out);

    k_agg<<<(NN + 1) / 2, 256, 0, stream>>>(rowptr, srcs, exs, nproj, hbuf);

    k_node_out<<<(NN + 63) / 64, 256, 0, stream>>>(hbuf, Won, bon, h_out);
}

// Round 11
// 633.987 us; speedup vs baseline: 2.7438x; 1.0239x over previous
//
#include <hip/hip_runtime.h>
#include <hip/hip_bf16.h>

// EGATConv fused forward, MI355X.
// R3: dst-CSR replaced 102.4M f32 atomics. R5/R6: edge GEMM -> bf16 MFMA.
// R9: coalesced epilogue gather + e_out MFMA (k_edge 352->253us, Occ 55%).
// R10: bf16 P-tables (FETCH 483->289MB, k_edge 230us) + k_agg 4x unroll.
// R11: aggregation path rebuilt on the linearity of @Won:
//   h_out = sum_h gather(ex * mproj_h)/den_h + bon,
//   mproj = nf@Wcomb + bcomb (bf16, 12.8MB), Wcomb[:,32h+c]=Wn_h@Won_h
//   precomposed in k_prepw. Fused k_aggout replaces k_agg+k_node_out:
//   gather bytes 410->205MB, hbuf 51MB roundtrip + one kernel eliminated.
// Algebra: stack@We = Psrc[src] + ef@We_mid + Pdst[dst]; a = f . rowsum(Wa);
// softmax max-shift skipped (|a|~0.3); normalization folded to node level.

#define NN 50000
#define NE 800000
#define NB ((NN + 255) / 256)   // 196 scan blocks

typedef __attribute__((ext_vector_type(8))) __bf16 bf16x8;
typedef __attribute__((ext_vector_type(4))) float f32x4;

__device__ __forceinline__ float lrelu(float x) { return x > 0.f ? x : 0.01f * x; }
__device__ __forceinline__ unsigned short f2bf(float x) {
    __bf16 b = (__bf16)x; return *reinterpret_cast<unsigned short*>(&b);
}
__device__ __forceinline__ float bf2f(unsigned short u) {
    __bf16 b = *reinterpret_cast<__bf16*>(&u); return (float)b;
}

// ---------------------------------------------------------------------------
// k_count: deg[n] = #edges with dst==n
// ---------------------------------------------------------------------------
__global__ __launch_bounds__(256) void k_count(const int* __restrict__ dst,
                                               int* __restrict__ deg)
{
    int i = blockIdx.x * blockDim.x + threadIdx.x;
    int stride = gridDim.x * blockDim.x;
    for (; i < NE; i += stride) atomicAdd(&deg[dst[i]], 1);
}

// ---------------------------------------------------------------------------
// 3-kernel exclusive scan of deg[NN] -> rowptr/cursor
// ---------------------------------------------------------------------------
__global__ __launch_bounds__(256) void k_scan_blk(const int* __restrict__ deg,
                                                  int* __restrict__ rowptr,
                                                  int* __restrict__ bsum)
{
    __shared__ int wsum[4];
    const int tid = threadIdx.x, lane = tid & 63, wid = tid >> 6;
    const int i = blockIdx.x * 256 + tid;
    int v = (i < NN) ? deg[i] : 0;
    int x = v;
    #pragma unroll
    for (int off = 1; off < 64; off <<= 1) {
        int t = __shfl_up(x, off);
        if (lane >= off) x += t;
    }
    if (lane == 63) wsum[wid] = x;
    __syncthreads();
    if (tid == 0) {
        int s = 0;
        #pragma unroll
        for (int w = 0; w < 4; ++w) { int t = wsum[w]; wsum[w] = s; s += t; }
        bsum[blockIdx.x] = s;
    }
    __syncthreads();
    if (i < NN) rowptr[i] = wsum[wid] + x - v;   // block-local exclusive
}

__global__ __launch_bounds__(256) void k_scan_top(int* __restrict__ bsum,
                                                  int* __restrict__ rowptr)
{
    __shared__ int wsum[4];
    const int tid = threadIdx.x, lane = tid & 63, wid = tid >> 6;
    int v = (tid < NB) ? bsum[tid] : 0;
    int x = v;
    #pragma unroll
    for (int off = 1; off < 64; off <<= 1) {
        int t = __shfl_up(x, off);
        if (lane >= off) x += t;
    }
    if (lane == 63) wsum[wid] = x;
    __syncthreads();
    if (tid == 0) {
        int s = 0;
        #pragma unroll
        for (int w = 0; w < 4; ++w) { int t = wsum[w]; wsum[w] = s; s += t; }
    }
    __syncthreads();
    int excl = wsum[wid] + x - v;
    if (tid < NB) bsum[tid] = excl;
    if (tid == NB - 1) rowptr[NN] = excl + v;    // total == NE
}

__global__ __launch_bounds__(256) void k_scan_add(int* __restrict__ rowptr,
                                                  const int* __restrict__ bsum,
                                                  int* __restrict__ cursor)
{
    const int i = blockIdx.x * 256 + threadIdx.x;
    if (i < NN) {
        int r = rowptr[i] + bsum[blockIdx.x];
        rowptr[i] = r;
        cursor[i] = r;
    }
}

// ---------------------------------------------------------------------------
// k_prepw: bf16 B-frag tables (We_mid, Woe), wa_sum, and the composed
// node->output weight: Wcomb[f][32h+c] = sum_f2 Wn[f][32h+f2]*Won[32h+f2][c],
// bcomb[32h+c] = sum_f2 bn[32h+f2]*Won[32h+f2][c].
// ---------------------------------------------------------------------------
__global__ __launch_bounds__(256) void k_prepw(const float* __restrict__ We,
                                               const float* __restrict__ Wa,
                                               const float* __restrict__ Woe,
                                               const float* __restrict__ Wn,
                                               const float* __restrict__ bn,
                                               const float* __restrict__ Won,
                                               unsigned short* __restrict__ Wefrag,
                                               unsigned short* __restrict__ Woefrag,
                                               float* __restrict__ wa_sum,
                                               float* __restrict__ Wcomb,
                                               float* __restrict__ bcomb)
{
    const int tid = threadIdx.x;
    if (tid < 32) {
        float4 w = *reinterpret_cast<const float4*>(&Wa[tid * 4]);
        wa_sum[tid] = w.x + w.y + w.z + w.w;
    }
    for (int idx = tid; idx < 8192; idx += 256) {
        int j = idx & 7, l = (idx >> 3) & 63, th = idx >> 9;
        int h = th & 1, t = th >> 1;
        int k = 32 * h + (l >> 4) * 8 + j;
        int c = 16 * t + (l & 15);
        Wefrag[idx] = f2bf(We[(64 + k) * 128 + c]);
    }
    for (int idx = tid; idx < 4096; idx += 256) {
        int j = idx & 7, l = (idx >> 3) & 63, uk = idx >> 9;
        int ks = uk & 3, u = uk >> 2;
        int k = 32 * ks + (l >> 4) * 8 + j;
        int c = 16 * u + (l & 15);
        Woefrag[idx] = f2bf(Woe[k * 32 + c]);
    }
    // Wcomb: 64x128, same [k][j] layout k_proj expects
    for (int idx = tid; idx < 8192; idx += 256) {
        int c = idx & 31, h = (idx >> 5) & 3, f = idx >> 7;
        float s = 0.f;
        #pragma unroll 8
        for (int f2 = 0; f2 < 32; ++f2)
            s = fmaf(Wn[f * 128 + 32 * h + f2], Won[(32 * h + f2) * 32 + c], s);
        Wcomb[f * 128 + 32 * h + c] = s;
    }
    if (tid < 128) {
        int c = tid & 31, h = tid >> 5;
        float s = 0.f;
        #pragma unroll 8
        for (int f2 = 0; f2 < 32; ++f2)
            s = fmaf(bn[32 * h + f2], Won[(32 * h + f2) * 32 + c], s);
        bcomb[tid] = s;
    }
}

// ---------------------------------------------------------------------------
// k_proj: mode 0: mproj = bf16(nf@Wcomb + bcomb);
//         mode 1/2: Psb/Pdb = bf16(nf@We_lo / nf@We_hi). All outputs bf16.
// ---------------------------------------------------------------------------
__global__ __launch_bounds__(256) void k_proj(
    const float* __restrict__ nf, const float* __restrict__ Wcomb,
    const float* __restrict__ bcomb, const float* __restrict__ We,
    unsigned short* __restrict__ mproj, unsigned short* __restrict__ Psb,
    unsigned short* __restrict__ Pdb)
{
    __shared__ __align__(16) float sA[64 * 68];
    __shared__ __align__(16) float sW[64 * 128];
    const int tid = threadIdx.x;
    const int mode = blockIdx.y;
    const int nBase = blockIdx.x * 64;

    const float* W = (mode == 0) ? Wcomb : (mode == 1 ? We : We + 128 * 128);
    unsigned short* outp = (mode == 0) ? mproj : (mode == 1 ? Psb : Pdb);

    #pragma unroll
    for (int q = 0; q < 4; ++q) {
        int idx = q * 256 + tid;
        int e = idx >> 4, c4 = idx & 15;
        int row = nBase + e;
        float4 v = make_float4(0.f, 0.f, 0.f, 0.f);
        if (row < NN) v = *reinterpret_cast<const float4*>(&nf[row * 64 + c4 * 4]);
        *reinterpret_cast<float4*>(&sA[e * 68 + c4 * 4]) = v;
    }
    #pragma unroll
    for (int q = 0; q < 8; ++q) {
        int idx = q * 256 + tid;
        *reinterpret_cast<float4*>(&sW[idx * 4]) =
            *reinterpret_cast<const float4*>(&W[idx * 4]);
    }
    __syncthreads();

    const int jt = tid & 15, et = tid >> 4;
    float acc[4][8];
    #pragma unroll
    for (int i = 0; i < 4; ++i)
        #pragma unroll
        for (int j = 0; j < 8; ++j) acc[i][j] = 0.f;

    #pragma unroll 2
    for (int kk4 = 0; kk4 < 16; ++kk4) {
        float4 a4[4];
        #pragma unroll
        for (int i = 0; i < 4; ++i)
            a4[i] = *reinterpret_cast<const float4*>(&sA[(4 * et + i) * 68 + 4 * kk4]);
        #pragma unroll
        for (int c = 0; c < 4; ++c) {
            int kk = 4 * kk4 + c;
            float4 b0 = *reinterpret_cast<const float4*>(&sW[kk * 128 + 4 * jt]);
            float4 b1 = *reinterpret_cast<const float4*>(&sW[kk * 128 + 64 + 4 * jt]);
            #pragma unroll
            for (int i = 0; i < 4; ++i) {
                float av = (&a4[i].x)[c];
                acc[i][0] = fmaf(av, b0.x, acc[i][0]);
                acc[i][1] = fmaf(av, b0.y, acc[i][1]);
                acc[i][2] = fmaf(av, b0.z, acc[i][2]);
                acc[i][3] = fmaf(av, b0.w, acc[i][3]);
                acc[i][4] = fmaf(av, b1.x, acc[i][4]);
                acc[i][5] = fmaf(av, b1.y, acc[i][5]);
                acc[i][6] = fmaf(av, b1.z, acc[i][6]);
                acc[i][7] = fmaf(av, b1.w, acc[i][7]);
            }
        }
    }

    float4 bias0 = make_float4(0.f, 0.f, 0.f, 0.f), bias1 = bias0;
    if (mode == 0) {
        bias0 = *reinterpret_cast<const float4*>(&bcomb[4 * jt]);
        bias1 = *reinterpret_cast<const float4*>(&bcomb[64 + 4 * jt]);
    }
    #pragma unroll
    for (int i = 0; i < 4; ++i) {
        int row = nBase + 4 * et + i;
        if (row >= NN) continue;
        ushort4 u0, u1;
        u0.x = f2bf(acc[i][0] + bias0.x); u0.y = f2bf(acc[i][1] + bias0.y);
        u0.z = f2bf(acc[i][2] + bias0.z); u0.w = f2bf(acc[i][3] + bias0.w);
        u1.x = f2bf(acc[i][4] + bias1.x); u1.y = f2bf(acc[i][5] + bias1.y);
        u1.z = f2bf(acc[i][6] + bias1.z); u1.w = f2bf(acc[i][7] + bias1.w);
        *reinterpret_cast<ushort4*>(&outp[(size_t)row * 128 + 4 * jt]) = u0;
        *reinterpret_cast<ushort4*>(&outp[(size_t)row * 128 + 64 + 4 * jt]) = u1;
    }
}

// ---------------------------------------------------------------------------
// k_edge (unchanged from R10, verified): 64 edges/block, 4 waves.
// ---------------------------------------------------------------------------
__global__ __launch_bounds__(256) void k_edge(
    const float* __restrict__ ef, const int* __restrict__ src,
    const int* __restrict__ dst,
    const unsigned short* __restrict__ Wefrag,
    const unsigned short* __restrict__ Woefrag,
    const float* __restrict__ wa_sum,
    const float* __restrict__ boe,
    const unsigned short* __restrict__ Psb, const unsigned short* __restrict__ Pdb,
    int* __restrict__ cursor, int* __restrict__ srcs,
    float* __restrict__ exs, float* __restrict__ e_out)
{
    __shared__ __align__(16) unsigned short fbuf[64 * 136];  // 17.4 KB
    __shared__ __align__(16) int sidx[128];     // src[0..63], dst[64..127]
    __shared__ __align__(16) float swa[32];

    const int tid = threadIdx.x;
    const int w = tid >> 6, l = tid & 63;
    const int g = l >> 4, c16 = l & 15;
    const int eBase = blockIdx.x * 64;
    const int rowBase = eBase + 16 * w;

    if (tid < 64) { sidx[tid] = src[eBase + tid]; sidx[64 + tid] = dst[eBase + tid]; }
    else if (tid < 96) swa[tid - 64] = wa_sum[tid - 64];

    // ---- ph1: A-frags from ef (row = c16, k = 32h + 8g + j), MFMA ----
    bf16x8 afrag[2];
    #pragma unroll
    for (int h = 0; h < 2; ++h) {
        const float* ap = &ef[(size_t)(rowBase + c16) * 64 + 32 * h + 8 * g];
        float4 a0 = *reinterpret_cast<const float4*>(ap);
        float4 a1 = *reinterpret_cast<const float4*>(ap + 4);
        bf16x8 v;
        v[0] = (__bf16)a0.x; v[1] = (__bf16)a0.y;
        v[2] = (__bf16)a0.z; v[3] = (__bf16)a0.w;
        v[4] = (__bf16)a1.x; v[5] = (__bf16)a1.y;
        v[6] = (__bf16)a1.z; v[7] = (__bf16)a1.w;
        afrag[h] = v;
    }

    f32x4 acc[8];
    #pragma unroll
    for (int t = 0; t < 8; ++t) {
        f32x4 z = {0.f, 0.f, 0.f, 0.f};
        acc[t] = z;
        #pragma unroll
        for (int h = 0; h < 2; ++h) {
            bf16x8 b = *reinterpret_cast<const bf16x8*>(
                &Wefrag[((size_t)(t * 2 + h) * 64 + l) * 8]);
            acc[t] = __builtin_amdgcn_mfma_f32_16x16x32_bf16(afrag[h], b, acc[t], 0, 0, 0);
        }
    }

    // ---- ph2: raw acc -> fbuf (bf16). C layout: row=4g+reg, col=16t+c16 ----
    #pragma unroll
    for (int t = 0; t < 8; ++t)
        #pragma unroll
        for (int r = 0; r < 4; ++r)
            fbuf[(16 * w + 4 * g + r) * 136 + 16 * t + c16] = f2bf(acc[t][r]);

    __syncthreads();   // B1

    // ---- ph3: thread=(e,q) owns cols {16j+4q..+3, j=0..7} of edge e ----
    {
        const int e = tid >> 2, q = tid & 3;
        const int s = sidx[e], d = sidx[64 + e];
        float4 wlo = *reinterpret_cast<const float4*>(&swa[4 * q]);
        float4 whi = *reinterpret_cast<const float4*>(&swa[16 + 4 * q]);
        float ah[4] = {0.f, 0.f, 0.f, 0.f};
        #pragma unroll
        for (int j = 0; j < 8; ++j) {
            int col = 16 * j + 4 * q;
            ushort4 psu = *reinterpret_cast<const ushort4*>(&Psb[(size_t)s * 128 + col]);
            ushort4 pdu = *reinterpret_cast<const ushort4*>(&Pdb[(size_t)d * 128 + col]);
            ushort4 rw = *reinterpret_cast<const ushort4*>(&fbuf[e * 136 + col]);
            float f0 = lrelu(bf2f(rw.x) + bf2f(psu.x) + bf2f(pdu.x));
            float f1 = lrelu(bf2f(rw.y) + bf2f(psu.y) + bf2f(pdu.y));
            float f2 = lrelu(bf2f(rw.z) + bf2f(psu.z) + bf2f(pdu.z));
            float f3 = lrelu(bf2f(rw.w) + bf2f(psu.w) + bf2f(pdu.w));
            const float4& wv = (j & 1) ? whi : wlo;
            int h = j >> 1;
            ah[h] = fmaf(f0, wv.x, ah[h]);
            ah[h] = fmaf(f1, wv.y, ah[h]);
            ah[h] = fmaf(f2, wv.z, ah[h]);
            ah[h] = fmaf(f3, wv.w, ah[h]);
            ushort4 fw;
            fw.x = f2bf(f0); fw.y = f2bf(f1); fw.z = f2bf(f2); fw.w = f2bf(f3);
            *reinterpret_cast<ushort4*>(&fbuf[e * 136 + col]) = fw;
        }
        // reduce heads across the 4 lanes of this edge
        #pragma unroll
        for (int h = 0; h < 4; ++h) {
            float v = ah[h];
            v += __shfl_xor(v, 1);
            v += __shfl_xor(v, 2);
            ah[h] = v;
        }
        // CSR fill
        int pos = 0;
        if (q == 0) pos = atomicAdd(&cursor[d], 1);
        pos = __shfl(pos, l & ~3);
        if (q == 0) srcs[pos] = s;
        float myA = (q == 0) ? ah[0] : (q == 1) ? ah[1] : (q == 2) ? ah[2] : ah[3];
        exs[(size_t)pos * 4 + q] = expf(myA);
    }

    __syncthreads();   // B2: f (bf16) ready for all rows

    // ---- ph4: e_out = f @ Woe + boe via MFMA ----
    {
        bf16x8 af[4];
        #pragma unroll
        for (int ks = 0; ks < 4; ++ks)
            af[ks] = *reinterpret_cast<const bf16x8*>(
                &fbuf[(16 * w + c16) * 136 + 32 * ks + 8 * g]);
        #pragma unroll
        for (int u = 0; u < 2; ++u) {
            f32x4 o = {0.f, 0.f, 0.f, 0.f};
            #pragma unroll
            for (int ks = 0; ks < 4; ++ks) {
                bf16x8 b = *reinterpret_cast<const bf16x8*>(
                    &Woefrag[((size_t)(u * 4 + ks) * 64 + l) * 8]);
                o = __builtin_amdgcn_mfma_f32_16x16x32_bf16(af[ks], b, o, 0, 0, 0);
            }
            float bo = boe[16 * u + c16];
            #pragma unroll
            for (int r = 0; r < 4; ++r)
                e_out[(size_t)(eBase + 16 * w + 4 * g + r) * 32 + 16 * u + c16] =
                    o[r] + bo;
        }
    }
}

// ---------------------------------------------------------------------------
// k_aggout (R11): fused gather + output projection.
// 8 nodes/block, thread=(node, c in [0,32)):
//   acc_h = sum_e ex_h * mproj[s][32h+c] ; den_h = sum_e ex_h
//   h_out[n][c] = (deg>0 ? sum_h acc_h/den_h : sum_h mproj[n][32h+c]) + bon[c]
// ---------------------------------------------------------------------------
__global__ __launch_bounds__(256) void k_aggout(
    const int* __restrict__ rowptr, const int* __restrict__ srcs,
    const float* __restrict__ exs, const unsigned short* __restrict__ mproj,
    const float* __restrict__ bon, float* __restrict__ h_out)
{
    const int tid = threadIdx.x;
    const int c = tid & 31;
    const int n = blockIdx.x * 8 + (tid >> 5);
    if (n >= NN) return;
    const int beg = rowptr[n], end = rowptr[n + 1];
    float a0 = 0.f, a1 = 0.f, a2 = 0.f, a3 = 0.f;
    float d0 = 0.f, d1 = 0.f, d2 = 0.f, d3 = 0.f;
    int p = beg;
    for (; p + 4 <= end; p += 4) {
        int s0 = srcs[p],     s1 = srcs[p + 1];
        int s2 = srcs[p + 2], s3 = srcs[p + 3];
        float4 e0 = *reinterpret_cast<const float4*>(&exs[(size_t)p * 4]);
        float4 e1 = *reinterpret_cast<const float4*>(&exs[(size_t)(p + 1) * 4]);
        float4 e2 = *reinterpret_cast<const float4*>(&exs[(size_t)(p + 2) * 4]);
        float4 e3 = *reinterpret_cast<const float4*>(&exs[(size_t)(p + 3) * 4]);
        const unsigned short* m0 = &mproj[(size_t)s0 * 128 + c];
        const unsigned short* m1 = &mproj[(size_t)s1 * 128 + c];
        const unsigned short* m2 = &mproj[(size_t)s2 * 128 + c];
        const unsigned short* m3 = &mproj[(size_t)s3 * 128 + c];
        a0 = fmaf(e0.x, bf2f(m0[0]),  a0); a1 = fmaf(e0.y, bf2f(m0[32]), a1);
        a2 = fmaf(e0.z, bf2f(m0[64]), a2); a3 = fmaf(e0.w, bf2f(m0[96]), a3);
        a0 = fmaf(e1.x, bf2f(m1[0]),  a0); a1 = fmaf(e1.y, bf2f(m1[32]), a1);
        a2 = fmaf(e1.z, bf2f(m1[64]), a2); a3 = fmaf(e1.w, bf2f(m1[96]), a3);
        a0 = fmaf(e2.x, bf2f(m2[0]),  a0); a1 = fmaf(e2.y, bf2f(m2[32]), a1);
        a2 = fmaf(e2.z, bf2f(m2[64]), a2); a3 = fmaf(e2.w, bf2f(m2[96]), a3);
        a0 = fmaf(e3.x, bf2f(m3[0]),  a0); a1 = fmaf(e3.y, bf2f(m3[32]), a1);
        a2 = fmaf(e3.z, bf2f(m3[64]), a2); a3 = fmaf(e3.w, bf2f(m3[96]), a3);
        d0 += e0.x + e1.x + e2.x + e3.x;
        d1 += e0.y + e1.y + e2.y + e3.y;
        d2 += e0.z + e1.z + e2.z + e3.z;
        d3 += e0.w + e1.w + e2.w + e3.w;
    }
    for (; p < end; ++p) {
        int s = srcs[p];
        float4 e = *reinterpret_cast<const float4*>(&exs[(size_t)p * 4]);
        const unsigned short* m = &mproj[(size_t)s * 128 + c];
        a0 = fmaf(e.x, bf2f(m[0]),  a0); a1 = fmaf(e.y, bf2f(m[32]), a1);
        a2 = fmaf(e.z, bf2f(m[64]), a2); a3 = fmaf(e.w, bf2f(m[96]), a3);
        d0 += e.x; d1 += e.y; d2 += e.z; d3 += e.w;
    }
    float out;
    if (end > beg) {
        out = a0 / d0 + a1 / d1 + a2 / d2 + a3 / d3;
    } else {
        const unsigned short* m = &mproj[(size_t)n * 128 + c];
        out = bf2f(m[0]) + bf2f(m[32]) + bf2f(m[64]) + bf2f(m[96]);
    }
    h_out[(size_t)n * 32 + c] = out + bon[c];
}

extern "C" void kernel_launch(void* const* d_in, const int* in_sizes, int n_in,
                              void* d_out, int out_size, void* d_ws, size_t ws_size,
                              hipStream_t stream) {
    const float* nfeats = (const float*)d_in[0];
    const float* efeats = (const float*)d_in[1];
    const int*   src    = (const int*)d_in[2];
    const int*   dst    = (const int*)d_in[3];
    const float* Wn     = (const float*)d_in[4];
    const float* bn     = (const float*)d_in[5];
    const float* We     = (const float*)d_in[6];
    const float* Wa     = (const float*)d_in[7];
    const float* Won    = (const float*)d_in[8];
    const float* bon    = (const float*)d_in[9];
    const float* Woe    = (const float*)d_in[10];
    const float* boe    = (const float*)d_in[11];

    float* h_out = (float*)d_out;                 // [N,32]
    float* e_out = h_out + (size_t)NN * 32;       // [E,32]

    // ws layout: mproj u16[N*128] | Psb u16[N*128] | Pdb u16[N*128] |
    //   exs f32[E*4] | deg[N]i | rowptr[N+1]i | cursor[N]i | srcs[E]i |
    //   bsum[256]i | wa_sum[32]f | Wefrag[8192]u16 | Woefrag[4096]u16 |
    //   Wcomb f32[8192] | bcomb f32[128]
    unsigned short* mproj = (unsigned short*)d_ws;
    unsigned short* Psb = mproj + (size_t)NN * 128;
    unsigned short* Pdb = Psb + (size_t)NN * 128;
    float* exs    = (float*)(Pdb + (size_t)NN * 128);
    int*   deg    = (int*)(exs + (size_t)NE * 4);
    int*   rowptr = deg + NN;
    int*   cursor = rowptr + NN + 1;
    int*   srcs   = cursor + NN;
    int*   bsum   = srcs + NE;
    float* wa_sum = (float*)(bsum + 256);
    unsigned short* Wefrag =
        (unsigned short*)(((uintptr_t)(wa_sum + 32) + 15) & ~(uintptr_t)15);
    unsigned short* Woefrag = Wefrag + 8192;
    float* Wcomb  = (float*)(Woefrag + 4096);
    float* bcomb  = Wcomb + 8192;

    hipMemsetAsync(deg, 0, NN * sizeof(int), stream);

    k_count<<<1024, 256, 0, stream>>>(dst, deg);
    k_scan_blk<<<NB, 256, 0, stream>>>(deg, rowptr, bsum);
    k_scan_top<<<1, 256, 0, stream>>>(bsum, rowptr);
    k_scan_add<<<NB, 256, 0, stream>>>(rowptr, bsum, cursor);

    k_prepw<<<1, 256, 0, stream>>>(We, Wa, Woe, Wn, bn, Won,
                                   Wefrag, Woefrag, wa_sum, Wcomb, bcomb);

    dim3 gProj((NN + 63) / 64, 3);
    k_proj<<<gProj, 256, 0, stream>>>(nfeats, Wcomb, bcomb, We, mproj, Psb, Pdb);

    k_edge<<<NE / 64, 256, 0, stream>>>(efeats, src, dst, Wefrag, Woefrag,
                                        wa_sum, boe, Psb, Pdb,
                                        cursor, srcs, exs, e_out);

    k_aggout<<<(NN + 7) / 8, 256, 0, stream>>>(rowptr, srcs, exs, mproj,
                                               bon, h_out);
}